// Round 10
// baseline (493.836 us; speedup 1.0000x reference)
//
#include <hip/hip_runtime.h>
#include <math.h>

// No FMA contraction: decision path rounds every op individually.
#pragma clang fp contract(off)

#define B 8
#define SP2 262144   // 512*512
#define SP3 65536    // 256*256

// ws float-indexed layout (~84 MB):
//  [0, 4194304)            imga f64 [8,512,512]        (K1->K3)
//  [4194304, 10485760)     pooled f32 [8,3,512,512]    (K1->K2a)
//  [4194304, 6291456)      codes uchar4 [8,512,512]    (K3 after K2a; ->K6)
//  [6291456, 8912896)      maskq u8 [8,5,512,512]      (K6 -> K7a)
//  [10485760, 15728640)    tri_h u16 [40,512,512]      (K7a -> K7b); rcs f64 [24,512,7] lives here K2a->K2b
//  [15728640, 20971520)    tri_v u16 [40,512,512]      (K7b -> K7c)
//  [0, 5242880)            h2buf f32 [40,512,256]      (K7c -> K7d; imga/pooled dead)
//  [20971520, ...)         tail: partial 32 dbl | thrLo 32 | thrHi 32 | ghist 816 | mn 40 | mx 40
#define POOLF  4194304
#define MASKQF 6291456
#define TRIHF  10485760
#define TRIVF  15728640
#define TAILF  20971520

// ---------------- K1: 3x3 s2 avgpool (f64) + channel mean ----------------
__global__ void k1_pool3(const float* __restrict__ x, float* __restrict__ pooled,
                         double* __restrict__ imga) {
    int idx = blockIdx.x * 256 + threadIdx.x;
    int xo = idx & 511;
    int yo = (idx >> 9) & 511;
    int b  = idx >> 18;
    int y0 = 2 * yo - 1, x0 = 2 * xo - 1;
    double pv[3];
    for (int c = 0; c < 3; ++c) {
        const float* p = x + ((size_t)(b * 3 + c)) * 1048576;
        double s = 0.0;
        #pragma unroll
        for (int dy = 0; dy < 3; ++dy) {
            int iy = y0 + dy;
            if ((unsigned)iy >= 1024u) continue;
            const float* row = p + (size_t)iy * 1024;
            #pragma unroll
            for (int dx = 0; dx < 3; ++dx) {
                int ix = x0 + dx;
                if ((unsigned)ix < 1024u) s += (double)row[ix];
            }
        }
        pv[c] = s / 9.0;
        pooled[((size_t)(b * 3 + c)) * SP2 + (idx & (SP2 - 1))] = (float)pv[c];
    }
    imga[idx] = ((pv[0] + pv[1]) + pv[2]) / 3.0;
}

// ---------------- K2a: per-(b,c,row) column-sublattice sums for the 7 kx offsets --------------
// C(kx) = { ix = 2*ox + (kx-3), ox in [0,256), ix in [0,512) }  <=>  d = ix-(kx-3) even, 0<=d<512
__global__ void k2a(const float* __restrict__ pooled, double* __restrict__ rcs) {
    int blk = blockIdx.x;            // (b*3+c)*512 + iy,  12288 blocks
    int iy = blk & 511;
    int bc = blk >> 9;
    const float* row = pooled + (size_t)bc * SP2 + iy * 512;
    double v[7] = {0, 0, 0, 0, 0, 0, 0};
    for (int ix = threadIdx.x; ix < 512; ix += 256) {
        double pv = (double)row[ix];
        #pragma unroll
        for (int kx = 0; kx < 7; ++kx) {
            int d = ix - (kx - 3);
            if (d >= 0 && d < 512 && !(d & 1)) v[kx] += pv;
        }
    }
    __shared__ double red[7][256];
    #pragma unroll
    for (int kx = 0; kx < 7; ++kx) red[kx][threadIdx.x] = v[kx];
    __syncthreads();
    for (int s = 128; s > 0; s >>= 1) {
        if (threadIdx.x < s) {
            #pragma unroll
            for (int kx = 0; kx < 7; ++kx)
                red[kx][threadIdx.x] += red[kx][threadIdx.x + s];
        }
        __syncthreads();
    }
    if (threadIdx.x < 7) rcs[(size_t)blk * 7 + threadIdx.x] = red[threadIdx.x][0];
}

// ---------------- K2b: combine -> conv spatial sum per (b, o=1..4) ----------------
__global__ void k2b(const double* __restrict__ rcs, const float* __restrict__ convw,
                    double* __restrict__ partial) {
    int b = blockIdx.x >> 2;
    int o = (blockIdx.x & 3) + 1;
    int t = threadIdx.x;             // 256 threads, 147 active
    double acc = 0.0;
    if (t < 147) {
        int c = t / 49;
        int k = t - c * 49;
        int ky = k / 7, kx = k - ky * 7;
        double w = (double)convw[o * 147 + t];
        const double* base = rcs + ((size_t)(b * 3 + c) * 512) * 7 + kx;
        double s = 0.0;
        for (int oy = 0; oy < 256; ++oy) {
            int iy = 2 * oy + ky - 3;
            if ((unsigned)iy < 512u) s += base[(size_t)iy * 7];
        }
        acc = w * s;
    }
    __shared__ double red[256];
    red[t] = acc;
    __syncthreads();
    for (int s2 = 128; s2 > 0; s2 >>= 1) {
        if (t < s2) red[t] += red[t + s2];
        __syncthreads();
    }
    if (t == 0) partial[blockIdx.x] = red[0];
}

// ---------------- K3: GL conv (f64) -> crisp + fuzzed bin codes, fused crisp histogram -------
__global__ void k3_gl(const double* __restrict__ imga, const float* __restrict__ weight,
                      uchar4* __restrict__ codes, int* __restrict__ ghist) {
    __shared__ double xv[101];
    __shared__ int h[102];
    for (int i = threadIdx.x; i < 101; i += 256) {
        double d = (double)i / 100.0;
        xv[i] = (double)(float)(10.0 * d * d * d);
    }
    for (int i = threadIdx.x; i < 102; i += 256) h[i] = 0;
    __syncthreads();
    int idx = blockIdx.x * 256 + threadIdx.x;
    int xo = idx & 511;
    int yo = (idx >> 9) & 511;
    int b  = idx >> 18;
    const double* im = imga + (size_t)b * SP2;
    double GL = (double)weight[0];
    double a1 = GL * 4.0, a2 = -a1 / 8.0, a3 = -a1 / 16.0;
    auto g = [&](int y, int x) -> double {
        if ((unsigned)y >= 512u || (unsigned)x >= 512u) return 0.0;
        return im[y * 512 + x];
    };
    double v = a1 * g(yo, xo)
             + a2 * (g(yo - 1, xo) + g(yo, xo - 1) + g(yo, xo + 1) + g(yo + 1, xo))
             + a3 * (g(yo - 2, xo) + g(yo - 1, xo - 1) + g(yo - 1, xo + 1) + g(yo, xo - 2)
                   + g(yo, xo + 2) + g(yo + 1, xo - 1) + g(yo + 1, xo + 1) + g(yo + 2, xo));
    double t = fabs(v);
    auto classify = [&](double u) -> int {
        if (u < 1e-6) return 255;
        if (u > xv[100]) return 101;
        int lo = 0, hi = 100;
        while (lo < hi) { int mid = (lo + hi) >> 1; if (u <= xv[mid]) hi = mid; else lo = mid + 1; }
        return lo;
    };
    const double EPS = 6e-7;
    int cM = classify(t);
    int cA = classify(t - EPS);
    int cB = classify(t + EPS);
    codes[idx] = make_uchar4((unsigned char)cM, (unsigned char)cA, (unsigned char)cB, 0);
    if (cM != 255) atomicAdd(&h[cM], 1);
    __syncthreads();
    // all threads in block share one b (block covers 256 consecutive idx within one image)
    for (int i = threadIdx.x; i < 102; i += 256)
        if (h[i]) atomicAdd(&ghist[b * 102 + i], h[i]);
}

// ---------------- K5: targets -> argmin with near-tie hedge (LDS, 1 block/batch) ------------
__global__ void k5_thr(const int* __restrict__ ghist, const double* __restrict__ partial,
                       const float* __restrict__ bn_gamma, const float* __restrict__ bn_beta,
                       const float* __restrict__ bn_mean, const float* __restrict__ bn_var,
                       int* __restrict__ thrLo, int* __restrict__ thrHi) {
    int b = blockIdx.x;
    int t = threadIdx.x;            // 128 threads
    __shared__ int    hS[102];
    __shared__ int    cumI[101];
    __shared__ double pct[101];
    __shared__ double ps[4];
    __shared__ int    allS;
    if (t < 102) hS[t] = ghist[b * 102 + t];
    __syncthreads();
    if (t == 0) {
        int all = 0;
        for (int k = 0; k < 102; ++k) all += hS[k];
        allS = all;
        int cum = 0;
        for (int k = 0; k < 101; ++k) { cum += hS[k]; cumI[k] = cum; }
    }
    __syncthreads();
    double alld = (double)allS;
    if (t < 101) pct[t] = (double)cumI[t] / alld;
    if (t < 4) {
        int o = t + 1;
        double s = partial[b * 4 + t];
        double m = s / 65536.0;
        double scale = (double)bn_gamma[o] / sqrt((double)bn_var[o] + 1e-5);
        double val = (m - (double)bn_mean[o]) * scale + (double)bn_beta[o];
        const double base[4] = {0.2, 0.4, 0.6, 0.8};
        ps[t] = base[t] + 0.05 * tanh(val);
    }
    __syncthreads();
    if (t == 0) {
        for (int i = 0; i < 4; ++i)
            for (int j = i + 1; j < 4; ++j)
                if (ps[j] < ps[i]) { double tp = ps[i]; ps[i] = ps[j]; ps[j] = tp; }
    }
    __syncthreads();
    if (t < 4) {
        const double EPS_TIE = 1.2e-7;
        double target = ps[t];
        double best = 1e300; int bi = 0;
        for (int k = 0; k < 101; ++k) {
            double z = fabs(pct[k] - target);
            if (z < best) { best = z; bi = k; }   // strict < => first occurrence
        }
        int lo = bi, hi = bi;
        for (int k = 0; k < 101; ++k) {
            double z = fabs(pct[k] - target);
            if (z <= best + EPS_TIE) { if (k < lo) lo = k; if (k > hi) hi = k; }
        }
        int cnt = cumI[hi] - cumI[lo];
        if (cnt > 2) { lo = bi; hi = bi; }
        thrLo[b * 4 + t] = lo;
        thrHi[b * 4 + t] = hi;
    }
}

// ---------------- K6: quarter-unit band mask (u8, values 0..4) ----------------
__global__ void k6_mask(const uchar4* __restrict__ codes, const int* __restrict__ thrLo,
                        const int* __restrict__ thrHi, unsigned char* __restrict__ mq) {
    int idx = blockIdx.x * 256 + threadIdx.x;
    int b = idx >> 18;
    int sp = idx & (SP2 - 1);
    uchar4 cd = codes[idx];
    const int* tL = thrLo + b * 4;
    const int* tH = thrHi + b * 4;
    int w0 = 0, w1 = 0, w2 = 0, w3 = 0, w4 = 0;
    int cand[2] = {cd.y, cd.z};
    #pragma unroll
    for (int ci = 0; ci < 2; ++ci) {
        int c = cand[ci];
        if (c == 255) continue;
        #pragma unroll
        for (int ti = 0; ti < 2; ++ti) {
            const int* t = ti ? tH : tL;
            if (c <= t[0]) ++w0;
            else if (c <= t[1]) ++w1;
            else if (c <= t[2]) ++w2;
            else if (c <= t[3]) ++w3;
            else ++w4;
        }
    }
    unsigned char* mb = mq + (size_t)b * 5 * SP2 + sp;
    mb[0]           = (unsigned char)w0;
    mb[SP2]         = (unsigned char)w1;
    mb[2 * SP2]     = (unsigned char)w2;
    mb[3 * SP2]     = (unsigned char)w3;
    mb[4 * SP2]     = (unsigned char)w4;
}

// ---------------- K7a/K7b: fused pool1+pool2 = separable 17-tap triangle, exact int -------------
__global__ void k7a(const unsigned char* __restrict__ q, unsigned short* __restrict__ out) {
    int idx = blockIdx.x * 256 + threadIdx.x;   // [40][512][512]
    int xo = idx & 511;
    const unsigned char* row = q + (size_t)(idx >> 9) * 512;
    int s = 0;
    if (xo >= 8 && xo <= 503) {
        #pragma unroll
        for (int m = -8; m <= 8; ++m) {
            int am = m < 0 ? -m : m;
            s += (9 - am) * (int)row[xo + m];
        }
    } else {
        int jlo = xo < 4 ? -xo : -4;
        int jhi = (511 - xo) < 4 ? (511 - xo) : 4;
        for (int m = -8; m <= 8; ++m) {
            int ix = xo + m;
            if ((unsigned)ix >= 512u) continue;
            int tw = 0;
            for (int j = jlo; j <= jhi; ++j) { int d = m - j; if (d >= -4 && d <= 4) ++tw; }
            s += tw * (int)row[ix];
        }
    }
    out[idx] = (unsigned short)s;   // <= 4*81 = 324
}

__global__ void k7b(const unsigned short* __restrict__ in, unsigned short* __restrict__ out) {
    int idx = blockIdx.x * 256 + threadIdx.x;   // [40][512][512]
    int xo = idx & 511;
    int y  = (idx >> 9) & 511;
    const unsigned short* cp = in + (size_t)(idx >> 18) * SP2;
    int s = 0;
    if (y >= 8 && y <= 503) {
        #pragma unroll
        for (int m = -8; m <= 8; ++m) {
            int am = m < 0 ? -m : m;
            s += (9 - am) * (int)cp[(y + m) * 512 + xo];
        }
    } else {
        int jlo = y < 4 ? -y : -4;
        int jhi = (511 - y) < 4 ? (511 - y) : 4;
        for (int m = -8; m <= 8; ++m) {
            int iy = y + m;
            if ((unsigned)iy >= 512u) continue;
            int tw = 0;
            for (int j = jlo; j <= jhi; ++j) { int d = m - j; if (d >= -4 && d <= 4) ++tw; }
            s += tw * (int)cp[iy * 512 + xo];
        }
    }
    out[idx] = (unsigned short)s;   // <= 81*324 = 26244
}

// ---------------- K7c/K7d: pool3 9x9 stride-2 (exact int in f32), K7d fuses min/max ----------
__global__ void k7c(const unsigned short* __restrict__ in, float* __restrict__ out) {
    int idx = blockIdx.x * 256 + threadIdx.x;   // [40][512][256]
    int xo = idx & 255;
    int y  = (idx >> 8) & 511;
    int ch = idx >> 17;
    const unsigned short* row = in + ((size_t)ch * 512 + y) * 512;
    int xb = 2 * xo - 4;
    int s = 0;
    #pragma unroll
    for (int d = 0; d < 9; ++d) {
        int ix = xb + d;
        if ((unsigned)ix < 512u) s += (int)row[ix];
    }
    out[idx] = (float)s;    // <= 236196, exact
}

__global__ void k7d(const float* __restrict__ in, float* __restrict__ out,
                    int* __restrict__ mn, int* __restrict__ mx) {
    int idx = blockIdx.x * 256 + threadIdx.x;   // [40][256][256]; block within one ch
    int xo = idx & 255;
    int y  = (idx >> 8) & 255;
    int ch = idx >> 16;
    const float* cp = in + (size_t)ch * 131072;
    int yb = 2 * y - 4;
    float s = 0.f;
    #pragma unroll
    for (int d = 0; d < 9; ++d) {
        int iy = yb + d;
        if ((unsigned)iy < 512u) s += cp[iy * 256 + xo];
    }
    float val = s / 2125764.0f;   // 4 * 81^3
    out[idx] = val;
    __shared__ float smn[256], smx[256];
    smn[threadIdx.x] = val; smx[threadIdx.x] = val;
    __syncthreads();
    for (int st = 128; st > 0; st >>= 1) {
        if (threadIdx.x < st) {
            smn[threadIdx.x] = fminf(smn[threadIdx.x], smn[threadIdx.x + st]);
            smx[threadIdx.x] = fmaxf(smx[threadIdx.x], smx[threadIdx.x + st]);
        }
        __syncthreads();
    }
    if (threadIdx.x == 0) {
        atomicMin(&mn[ch], __float_as_int(smn[0]));   // valid: all values >= 0
        atomicMax(&mx[ch], __float_as_int(smx[0]));
    }
}

__global__ void k9_norm(float* __restrict__ o, const int* __restrict__ mn,
                        const int* __restrict__ mx) {
    int idx = blockIdx.x * 256 + threadIdx.x;
    int ch = idx >> 16;
    float a = __int_as_float(mn[ch]);
    float bmax = __int_as_float(mx[ch]);
    o[idx] = (o[idx] - a) / (bmax - a);
}

extern "C" void kernel_launch(void* const* d_in, const int* in_sizes, int n_in,
                              void* d_out, int out_size, void* d_ws, size_t ws_size,
                              hipStream_t stream) {
    const float* x      = (const float*)d_in[0];
    const float* weight = (const float*)d_in[1];
    const float* conv_w = (const float*)d_in[2];
    const float* bn_g   = (const float*)d_in[3];
    const float* bn_b   = (const float*)d_in[4];
    const float* bn_m   = (const float*)d_in[5];
    const float* bn_v   = (const float*)d_in[6];
    float* out = (float*)d_out;
    float* ws  = (float*)d_ws;

    double* imga   = (double*)ws;
    float*  pooled = ws + POOLF;
    uchar4* codes  = (uchar4*)(ws + POOLF);            // overlaps pooled; written after K2a
    unsigned char* maskq = (unsigned char*)(ws + MASKQF);
    double* rcs    = (double*)(ws + TRIHF);            // 24*512*7 doubles; dead before k7a writes triH
    unsigned short* triH = (unsigned short*)(ws + TRIHF);
    unsigned short* triV = (unsigned short*)(ws + TRIVF);
    float*  h2buf  = ws;                               // overlaps imga/pooled (dead by K7c)
    double* partial = (double*)(ws + TAILF);           // 32 doubles
    int*    thrLo   = (int*)(ws + TAILF + 4096);
    int*    thrHi   = thrLo + 32;
    int*    ghist   = thrHi + 32;
    int*    mn      = ghist + 816;
    int*    mx      = mn + 40;

    hipMemsetAsync(ghist, 0, 816 * sizeof(int), stream);
    hipMemsetAsync(mn, 0x7F, 40 * sizeof(int), stream);   // 0x7F7F7F7F = 3.39e38f
    hipMemsetAsync(mx, 0, 40 * sizeof(int), stream);

    k1_pool3  <<<8192, 256, 0, stream>>>(x, pooled, imga);
    k2a       <<<12288, 256, 0, stream>>>(pooled, rcs);
    k2b       <<<32, 256, 0, stream>>>(rcs, conv_w, partial);
    k3_gl     <<<8192, 256, 0, stream>>>(imga, weight, codes, ghist);
    k5_thr    <<<B, 128, 0, stream>>>(ghist, partial, bn_g, bn_b, bn_m, bn_v, thrLo, thrHi);
    k6_mask   <<<8192, 256, 0, stream>>>(codes, thrLo, thrHi, maskq);
    k7a       <<<40960, 256, 0, stream>>>(maskq, triH);
    k7b       <<<40960, 256, 0, stream>>>(triH, triV);
    k7c       <<<20480, 256, 0, stream>>>(triV, h2buf);
    k7d       <<<10240, 256, 0, stream>>>(h2buf, out, mn, mx);
    k9_norm   <<<10240, 256, 0, stream>>>(out, mn, mx);
}

// Round 11
// 359.833 us; speedup vs baseline: 1.3724x; 1.3724x over previous
//
#include <hip/hip_runtime.h>
#include <math.h>

// No FMA contraction: decision path rounds every op individually.
#pragma clang fp contract(off)

#define B 8
#define SP2 262144   // 512*512
#define SP3 65536    // 256*256

// ws float-indexed layout (~84 MB):
//  [0, 4194304)            imga f64 [8,512,512]        (K1->K3)
//  [4194304, 10485760)     pooled f32 [8,3,512,512]    (K1->K2a)
//  [4194304, 6291456)      codes uchar4 [8,512,512]    (K3 after K2a; ->K6)
//  [6291456, 8912896)      maskq u8 [8,5,512,512]      (K6 -> K7a)
//  [10485760, 15728640)    tri_h u16 [40,512,512]      (K7a -> K7b); rcs f64 [24,512,7] K2a->K2b
//  [15728640, 20971520)    tri_v u16 [40,512,512]      (K7b -> K7c)
//  [0, 5242880)            h2buf f32 [40,512,256]      (K7c -> K7d; imga/pooled dead)
//  [20971520, ...)         tail: partial 32 dbl | thrLo 32 | thrHi 32 | ghist 816 |
//                                pmn 10240 f | pmx 10240 f | mn 40 f | mx 40 f
#define POOLF  4194304
#define MASKQF 6291456
#define TRIHF  10485760
#define TRIVF  15728640
#define TAILF  20971520

// ---------------- K1: 3x3 s2 avgpool (f64) + channel mean ----------------
__global__ void k1_pool3(const float* __restrict__ x, float* __restrict__ pooled,
                         double* __restrict__ imga) {
    int idx = blockIdx.x * 256 + threadIdx.x;
    int xo = idx & 511;
    int yo = (idx >> 9) & 511;
    int b  = idx >> 18;
    int y0 = 2 * yo - 1, x0 = 2 * xo - 1;
    double pv[3];
    for (int c = 0; c < 3; ++c) {
        const float* p = x + ((size_t)(b * 3 + c)) * 1048576;
        double s = 0.0;
        #pragma unroll
        for (int dy = 0; dy < 3; ++dy) {
            int iy = y0 + dy;
            if ((unsigned)iy >= 1024u) continue;
            const float* row = p + (size_t)iy * 1024;
            #pragma unroll
            for (int dx = 0; dx < 3; ++dx) {
                int ix = x0 + dx;
                if ((unsigned)ix < 1024u) s += (double)row[ix];
            }
        }
        pv[c] = s / 9.0;
        pooled[((size_t)(b * 3 + c)) * SP2 + (idx & (SP2 - 1))] = (float)pv[c];
    }
    imga[idx] = ((pv[0] + pv[1]) + pv[2]) / 3.0;
}

// ---------------- K2a: per-(b,c,row) column-sublattice sums for the 7 kx offsets --------------
__global__ void k2a(const float* __restrict__ pooled, double* __restrict__ rcs) {
    int blk = blockIdx.x;            // (b*3+c)*512 + iy,  12288 blocks
    int iy = blk & 511;
    int bc = blk >> 9;
    const float* row = pooled + (size_t)bc * SP2 + iy * 512;
    double v[7] = {0, 0, 0, 0, 0, 0, 0};
    for (int ix = threadIdx.x; ix < 512; ix += 256) {
        double pv = (double)row[ix];
        #pragma unroll
        for (int kx = 0; kx < 7; ++kx) {
            int d = ix - (kx - 3);
            if (d >= 0 && d < 512 && !(d & 1)) v[kx] += pv;
        }
    }
    __shared__ double red[7][256];
    #pragma unroll
    for (int kx = 0; kx < 7; ++kx) red[kx][threadIdx.x] = v[kx];
    __syncthreads();
    for (int s = 128; s > 0; s >>= 1) {
        if (threadIdx.x < s) {
            #pragma unroll
            for (int kx = 0; kx < 7; ++kx)
                red[kx][threadIdx.x] += red[kx][threadIdx.x + s];
        }
        __syncthreads();
    }
    if (threadIdx.x < 7) rcs[(size_t)blk * 7 + threadIdx.x] = red[threadIdx.x][0];
}

// ---------------- K2b: combine -> conv spatial sum per (b, o=1..4) ----------------
__global__ void k2b(const double* __restrict__ rcs, const float* __restrict__ convw,
                    double* __restrict__ partial) {
    int b = blockIdx.x >> 2;
    int o = (blockIdx.x & 3) + 1;
    int t = threadIdx.x;             // 256 threads, 147 active
    double acc = 0.0;
    if (t < 147) {
        int c = t / 49;
        int k = t - c * 49;
        int ky = k / 7, kx = k - ky * 7;
        double w = (double)convw[o * 147 + t];
        const double* base = rcs + ((size_t)(b * 3 + c) * 512) * 7 + kx;
        double s = 0.0;
        for (int oy = 0; oy < 256; ++oy) {
            int iy = 2 * oy + ky - 3;
            if ((unsigned)iy < 512u) s += base[(size_t)iy * 7];
        }
        acc = w * s;
    }
    __shared__ double red[256];
    red[t] = acc;
    __syncthreads();
    for (int s2 = 128; s2 > 0; s2 >>= 1) {
        if (t < s2) red[t] += red[t + s2];
        __syncthreads();
    }
    if (t == 0) partial[blockIdx.x] = red[0];
}

// ---------------- K3: GL conv (f64) -> crisp + fuzzed bin codes ----------------
__global__ void k3_gl(const double* __restrict__ imga, const float* __restrict__ weight,
                      uchar4* __restrict__ codes) {
    __shared__ double xv[101];
    for (int i = threadIdx.x; i < 101; i += 256) {
        double d = (double)i / 100.0;
        xv[i] = (double)(float)(10.0 * d * d * d);
    }
    __syncthreads();
    int idx = blockIdx.x * 256 + threadIdx.x;
    int xo = idx & 511;
    int yo = (idx >> 9) & 511;
    int b  = idx >> 18;
    const double* im = imga + (size_t)b * SP2;
    double GL = (double)weight[0];
    double a1 = GL * 4.0, a2 = -a1 / 8.0, a3 = -a1 / 16.0;
    auto g = [&](int y, int x) -> double {
        if ((unsigned)y >= 512u || (unsigned)x >= 512u) return 0.0;
        return im[y * 512 + x];
    };
    double v = a1 * g(yo, xo)
             + a2 * (g(yo - 1, xo) + g(yo, xo - 1) + g(yo, xo + 1) + g(yo + 1, xo))
             + a3 * (g(yo - 2, xo) + g(yo - 1, xo - 1) + g(yo - 1, xo + 1) + g(yo, xo - 2)
                   + g(yo, xo + 2) + g(yo + 1, xo - 1) + g(yo + 1, xo + 1) + g(yo + 2, xo));
    double t = fabs(v);
    auto classify = [&](double u) -> int {
        if (u < 1e-6) return 255;
        if (u > xv[100]) return 101;
        int lo = 0, hi = 100;
        while (lo < hi) { int mid = (lo + hi) >> 1; if (u <= xv[mid]) hi = mid; else lo = mid + 1; }
        return lo;
    };
    const double EPS = 6e-7;
    int cM = classify(t);
    int cA = classify(t - EPS);
    int cB = classify(t + EPS);
    codes[idx] = make_uchar4((unsigned char)cM, (unsigned char)cA, (unsigned char)cB, 0);
}

// ---------------- K4: per-batch crisp-code histogram (512 blocks, low atomic pressure) --------
__global__ void k4_hist(const uchar4* __restrict__ codes, int* __restrict__ ghist) {
    int b = blockIdx.y;
    __shared__ int h[102];
    for (int i = threadIdx.x; i < 102; i += 256) h[i] = 0;
    __syncthreads();
    const uchar4* cb = codes + (size_t)b * SP2;
    for (int p = blockIdx.x * 256 + threadIdx.x; p < SP2; p += 64 * 256) {
        int c = cb[p].x;
        if (c != 255) atomicAdd(&h[c], 1);
    }
    __syncthreads();
    for (int i = threadIdx.x; i < 102; i += 256)
        if (h[i]) atomicAdd(&ghist[b * 102 + i], h[i]);
}

// ---------------- K5: targets -> argmin with near-tie hedge (LDS, 1 block/batch) ------------
__global__ void k5_thr(const int* __restrict__ ghist, const double* __restrict__ partial,
                       const float* __restrict__ bn_gamma, const float* __restrict__ bn_beta,
                       const float* __restrict__ bn_mean, const float* __restrict__ bn_var,
                       int* __restrict__ thrLo, int* __restrict__ thrHi) {
    int b = blockIdx.x;
    int t = threadIdx.x;            // 128 threads
    __shared__ int    hS[102];
    __shared__ int    cumI[101];
    __shared__ double pct[101];
    __shared__ double ps[4];
    __shared__ int    allS;
    if (t < 102) hS[t] = ghist[b * 102 + t];
    __syncthreads();
    if (t == 0) {
        int all = 0;
        for (int k = 0; k < 102; ++k) all += hS[k];
        allS = all;
        int cum = 0;
        for (int k = 0; k < 101; ++k) { cum += hS[k]; cumI[k] = cum; }
    }
    __syncthreads();
    double alld = (double)allS;
    if (t < 101) pct[t] = (double)cumI[t] / alld;
    if (t < 4) {
        int o = t + 1;
        double s = partial[b * 4 + t];
        double m = s / 65536.0;
        double scale = (double)bn_gamma[o] / sqrt((double)bn_var[o] + 1e-5);
        double val = (m - (double)bn_mean[o]) * scale + (double)bn_beta[o];
        const double base[4] = {0.2, 0.4, 0.6, 0.8};
        ps[t] = base[t] + 0.05 * tanh(val);
    }
    __syncthreads();
    if (t == 0) {
        for (int i = 0; i < 4; ++i)
            for (int j = i + 1; j < 4; ++j)
                if (ps[j] < ps[i]) { double tp = ps[i]; ps[i] = ps[j]; ps[j] = tp; }
    }
    __syncthreads();
    if (t < 4) {
        const double EPS_TIE = 1.2e-7;
        double target = ps[t];
        double best = 1e300; int bi = 0;
        for (int k = 0; k < 101; ++k) {
            double z = fabs(pct[k] - target);
            if (z < best) { best = z; bi = k; }   // strict < => first occurrence
        }
        int lo = bi, hi = bi;
        for (int k = 0; k < 101; ++k) {
            double z = fabs(pct[k] - target);
            if (z <= best + EPS_TIE) { if (k < lo) lo = k; if (k > hi) hi = k; }
        }
        int cnt = cumI[hi] - cumI[lo];
        if (cnt > 2) { lo = bi; hi = bi; }
        thrLo[b * 4 + t] = lo;
        thrHi[b * 4 + t] = hi;
    }
}

// ---------------- K6: quarter-unit band mask (u8, values 0..4) ----------------
__global__ void k6_mask(const uchar4* __restrict__ codes, const int* __restrict__ thrLo,
                        const int* __restrict__ thrHi, unsigned char* __restrict__ mq) {
    int idx = blockIdx.x * 256 + threadIdx.x;
    int b = idx >> 18;
    int sp = idx & (SP2 - 1);
    uchar4 cd = codes[idx];
    const int* tL = thrLo + b * 4;
    const int* tH = thrHi + b * 4;
    int w0 = 0, w1 = 0, w2 = 0, w3 = 0, w4 = 0;
    int cand[2] = {cd.y, cd.z};
    #pragma unroll
    for (int ci = 0; ci < 2; ++ci) {
        int c = cand[ci];
        if (c == 255) continue;
        #pragma unroll
        for (int ti = 0; ti < 2; ++ti) {
            const int* t = ti ? tH : tL;
            if (c <= t[0]) ++w0;
            else if (c <= t[1]) ++w1;
            else if (c <= t[2]) ++w2;
            else if (c <= t[3]) ++w3;
            else ++w4;
        }
    }
    unsigned char* mb = mq + (size_t)b * 5 * SP2 + sp;
    mb[0]           = (unsigned char)w0;
    mb[SP2]         = (unsigned char)w1;
    mb[2 * SP2]     = (unsigned char)w2;
    mb[3 * SP2]     = (unsigned char)w3;
    mb[4 * SP2]     = (unsigned char)w4;
}

// ---------------- K7a: horizontal 17-tap triangle (pool1+pool2 h), exact int ----------------
__global__ void k7a(const unsigned char* __restrict__ q, unsigned short* __restrict__ out) {
    int idx = blockIdx.x * 256 + threadIdx.x;   // [40][512][512]
    int xo = idx & 511;
    const unsigned char* row = q + (size_t)(idx >> 9) * 512;
    int s = 0;
    if (xo >= 8 && xo <= 503) {
        #pragma unroll
        for (int m = -8; m <= 8; ++m) {
            int am = m < 0 ? -m : m;
            s += (9 - am) * (int)row[xo + m];
        }
    } else {
        int jlo = xo < 4 ? -xo : -4;
        int jhi = (511 - xo) < 4 ? (511 - xo) : 4;
        for (int m = -8; m <= 8; ++m) {
            int ix = xo + m;
            if ((unsigned)ix >= 512u) continue;
            int tw = 0;
            for (int j = jlo; j <= jhi; ++j) { int d = m - j; if (d >= -4 && d <= 4) ++tw; }
            s += tw * (int)row[ix];
        }
    }
    out[idx] = (unsigned short)s;   // <= 4*81 = 324
}

// ---------------- K7b: vertical 17-tap triangle, XCD-swizzled for L2 row reuse --------------
__global__ void k7b(const unsigned short* __restrict__ in, unsigned short* __restrict__ out) {
    // bijective XCD swizzle: nwg=40960, q=5120 -> each XCD owns contiguous (ch,y) range
    int w = (blockIdx.x & 7) * 5120 + (blockIdx.x >> 3);
    int idx = w * 256 + threadIdx.x;            // [40][512][512]
    int xo = idx & 511;
    int y  = (idx >> 9) & 511;
    const unsigned short* cp = in + (size_t)(idx >> 18) * SP2;
    int s = 0;
    if (y >= 8 && y <= 503) {
        #pragma unroll
        for (int m = -8; m <= 8; ++m) {
            int am = m < 0 ? -m : m;
            s += (9 - am) * (int)cp[(y + m) * 512 + xo];
        }
    } else {
        int jlo = y < 4 ? -y : -4;
        int jhi = (511 - y) < 4 ? (511 - y) : 4;
        for (int m = -8; m <= 8; ++m) {
            int iy = y + m;
            if ((unsigned)iy >= 512u) continue;
            int tw = 0;
            for (int j = jlo; j <= jhi; ++j) { int d = m - j; if (d >= -4 && d <= 4) ++tw; }
            s += tw * (int)cp[iy * 512 + xo];
        }
    }
    out[idx] = (unsigned short)s;   // <= 81*324 = 26244
}

// ---------------- K7c: horizontal 9-tap stride-2 (exact int in f32) ----------------
__global__ void k7c(const unsigned short* __restrict__ in, float* __restrict__ out) {
    int idx = blockIdx.x * 256 + threadIdx.x;   // [40][512][256]
    int xo = idx & 255;
    int y  = (idx >> 8) & 511;
    int ch = idx >> 17;
    const unsigned short* row = in + ((size_t)ch * 512 + y) * 512;
    int xb = 2 * xo - 4;
    int s = 0;
    #pragma unroll
    for (int d = 0; d < 9; ++d) {
        int ix = xb + d;
        if ((unsigned)ix < 512u) s += (int)row[ix];
    }
    out[idx] = (float)s;    // <= 236196, exact
}

// ---------------- K7d: vertical 9-tap stride-2, XCD-swizzled; per-block min/max partials -----
__global__ void k7d(const float* __restrict__ in, float* __restrict__ out,
                    float* __restrict__ pmn, float* __restrict__ pmx) {
    // bijective XCD swizzle: nwg=10240, q=1280
    int w = (blockIdx.x & 7) * 1280 + (blockIdx.x >> 3);
    int idx = w * 256 + threadIdx.x;            // [40][256][256]; block = one row of one ch
    int xo = idx & 255;
    int y  = (idx >> 8) & 255;
    int ch = idx >> 16;
    const float* cp = in + (size_t)ch * 131072;
    int yb = 2 * y - 4;
    float s = 0.f;
    #pragma unroll
    for (int d = 0; d < 9; ++d) {
        int iy = yb + d;
        if ((unsigned)iy < 512u) s += cp[iy * 256 + xo];
    }
    float val = s / 2125764.0f;   // 4 * 81^3
    out[idx] = val;
    __shared__ float smn[256], smx[256];
    smn[threadIdx.x] = val; smx[threadIdx.x] = val;
    __syncthreads();
    for (int st = 128; st > 0; st >>= 1) {
        if (threadIdx.x < st) {
            smn[threadIdx.x] = fminf(smn[threadIdx.x], smn[threadIdx.x + st]);
            smx[threadIdx.x] = fmaxf(smx[threadIdx.x], smx[threadIdx.x + st]);
        }
        __syncthreads();
    }
    if (threadIdx.x == 0) { pmn[w] = smn[0]; pmx[w] = smx[0]; }
}

// ---------------- K8b: reduce 256 partials per channel (atomic-free) ----------------
__global__ void k8b(const float* __restrict__ pmn, const float* __restrict__ pmx,
                    float* __restrict__ mn, float* __restrict__ mx) {
    int ch = blockIdx.x;
    __shared__ float smn[256], smx[256];
    smn[threadIdx.x] = pmn[ch * 256 + threadIdx.x];
    smx[threadIdx.x] = pmx[ch * 256 + threadIdx.x];
    __syncthreads();
    for (int st = 128; st > 0; st >>= 1) {
        if (threadIdx.x < st) {
            smn[threadIdx.x] = fminf(smn[threadIdx.x], smn[threadIdx.x + st]);
            smx[threadIdx.x] = fmaxf(smx[threadIdx.x], smx[threadIdx.x + st]);
        }
        __syncthreads();
    }
    if (threadIdx.x == 0) { mn[ch] = smn[0]; mx[ch] = smx[0]; }
}

__global__ void k9_norm(float* __restrict__ o, const float* __restrict__ mn,
                        const float* __restrict__ mx) {
    int idx = blockIdx.x * 256 + threadIdx.x;
    int ch = idx >> 16;
    float a = mn[ch];
    o[idx] = (o[idx] - a) / (mx[ch] - a);
}

extern "C" void kernel_launch(void* const* d_in, const int* in_sizes, int n_in,
                              void* d_out, int out_size, void* d_ws, size_t ws_size,
                              hipStream_t stream) {
    const float* x      = (const float*)d_in[0];
    const float* weight = (const float*)d_in[1];
    const float* conv_w = (const float*)d_in[2];
    const float* bn_g   = (const float*)d_in[3];
    const float* bn_b   = (const float*)d_in[4];
    const float* bn_m   = (const float*)d_in[5];
    const float* bn_v   = (const float*)d_in[6];
    float* out = (float*)d_out;
    float* ws  = (float*)d_ws;

    double* imga   = (double*)ws;
    float*  pooled = ws + POOLF;
    uchar4* codes  = (uchar4*)(ws + POOLF);            // overlaps pooled; written after K2a
    unsigned char* maskq = (unsigned char*)(ws + MASKQF);
    double* rcs    = (double*)(ws + TRIHF);            // 24*512*7 doubles; dead before k7a writes triH
    unsigned short* triH = (unsigned short*)(ws + TRIHF);
    unsigned short* triV = (unsigned short*)(ws + TRIVF);
    float*  h2buf  = ws;                               // overlaps imga/pooled (dead by K7c)
    double* partial = (double*)(ws + TAILF);           // 32 doubles
    int*    thrLo   = (int*)(ws + TAILF + 4096);
    int*    thrHi   = thrLo + 32;
    int*    ghist   = thrHi + 32;
    float*  pmn     = (float*)(ghist + 816);           // 10240
    float*  pmx     = pmn + 10240;                     // 10240
    float*  mn      = pmx + 10240;                     // 40
    float*  mx      = mn + 40;                         // 40

    hipMemsetAsync(ghist, 0, 816 * sizeof(int), stream);

    k1_pool3  <<<8192, 256, 0, stream>>>(x, pooled, imga);
    k2a       <<<12288, 256, 0, stream>>>(pooled, rcs);
    k2b       <<<32, 256, 0, stream>>>(rcs, conv_w, partial);
    k3_gl     <<<8192, 256, 0, stream>>>(imga, weight, codes);
    k4_hist   <<<dim3(64, B), 256, 0, stream>>>(codes, ghist);
    k5_thr    <<<B, 128, 0, stream>>>(ghist, partial, bn_g, bn_b, bn_m, bn_v, thrLo, thrHi);
    k6_mask   <<<8192, 256, 0, stream>>>(codes, thrLo, thrHi, maskq);
    k7a       <<<40960, 256, 0, stream>>>(maskq, triH);
    k7b       <<<40960, 256, 0, stream>>>(triH, triV);
    k7c       <<<20480, 256, 0, stream>>>(triV, h2buf);
    k7d       <<<10240, 256, 0, stream>>>(h2buf, out, pmn, pmx);
    k8b       <<<40, 256, 0, stream>>>(pmn, pmx, mn, mx);
    k9_norm   <<<10240, 256, 0, stream>>>(out, mn, mx);
}

// Round 12
// 243.718 us; speedup vs baseline: 2.0263x; 1.4764x over previous
//
#include <hip/hip_runtime.h>
#include <math.h>

// No FMA contraction: decision path rounds every op individually.
#pragma clang fp contract(off)

#define B 8
#define SP2 262144   // 512*512
#define SP3 65536    // 256*256

// ws float-indexed layout (~84 MB):
//  [0, 4194304)            imga f64 [8,512,512]        (K1->K3)
//  [4194304, 10485760)     pooled f32 [8,3,512,512]    (K1->K2a)
//  [4194304, 6291456)      codes uchar4 [8,512,512]    (K3 after K2a; ->K6)
//  [6291456, 8912896)      maskq u8 [8,5,512,512]      (K6 -> K7a)
//  [10485760, 15728640)    tri_h u16 [40,512,512]      (K7a -> K7b); rcs f64 [24,512,7] K2a->K2b
//  [15728640, 20971520)    tri_v u16 [40,512,512]      (K7b -> K7c)
//  [0, 5242880)            h2buf f32 [40,512,256]      (K7c -> K7d; imga/pooled dead)
//  [20971520, ...)         tail: partial 32 dbl | thrLo 32 | thrHi 32 | ghist 816 |
//                                pmn 10240 f | pmx 10240 f | mn 40 f | mx 40 f
#define POOLF  4194304
#define MASKQF 6291456
#define TRIHF  10485760
#define TRIVF  15728640
#define TAILF  20971520

// ---------------- K1: 3x3 s2 avgpool (f64) + channel mean ----------------
__global__ void k1_pool3(const float* __restrict__ x, float* __restrict__ pooled,
                         double* __restrict__ imga) {
    int idx = blockIdx.x * 256 + threadIdx.x;
    int xo = idx & 511;
    int yo = (idx >> 9) & 511;
    int b  = idx >> 18;
    int y0 = 2 * yo - 1, x0 = 2 * xo - 1;
    double pv[3];
    for (int c = 0; c < 3; ++c) {
        const float* p = x + ((size_t)(b * 3 + c)) * 1048576;
        double s = 0.0;
        #pragma unroll
        for (int dy = 0; dy < 3; ++dy) {
            int iy = y0 + dy;
            if ((unsigned)iy >= 1024u) continue;
            const float* row = p + (size_t)iy * 1024;
            #pragma unroll
            for (int dx = 0; dx < 3; ++dx) {
                int ix = x0 + dx;
                if ((unsigned)ix < 1024u) s += (double)row[ix];
            }
        }
        pv[c] = s / 9.0;
        pooled[((size_t)(b * 3 + c)) * SP2 + (idx & (SP2 - 1))] = (float)pv[c];
    }
    imga[idx] = ((pv[0] + pv[1]) + pv[2]) / 3.0;
}

// ---------------- K2a: per-(b,c,row) column-sublattice sums for the 7 kx offsets --------------
__global__ void k2a(const float* __restrict__ pooled, double* __restrict__ rcs) {
    int blk = blockIdx.x;            // (b*3+c)*512 + iy,  12288 blocks
    int iy = blk & 511;
    int bc = blk >> 9;
    const float* row = pooled + (size_t)bc * SP2 + iy * 512;
    double v[7] = {0, 0, 0, 0, 0, 0, 0};
    for (int ix = threadIdx.x; ix < 512; ix += 256) {
        double pv = (double)row[ix];
        #pragma unroll
        for (int kx = 0; kx < 7; ++kx) {
            int d = ix - (kx - 3);
            if (d >= 0 && d < 512 && !(d & 1)) v[kx] += pv;
        }
    }
    __shared__ double red[7][256];
    #pragma unroll
    for (int kx = 0; kx < 7; ++kx) red[kx][threadIdx.x] = v[kx];
    __syncthreads();
    for (int s = 128; s > 0; s >>= 1) {
        if (threadIdx.x < s) {
            #pragma unroll
            for (int kx = 0; kx < 7; ++kx)
                red[kx][threadIdx.x] += red[kx][threadIdx.x + s];
        }
        __syncthreads();
    }
    if (threadIdx.x < 7) rcs[(size_t)blk * 7 + threadIdx.x] = red[threadIdx.x][0];
}

// ---------------- K2b: combine -> conv spatial sum per (b, o=1..4) ----------------
__global__ void k2b(const double* __restrict__ rcs, const float* __restrict__ convw,
                    double* __restrict__ partial) {
    int b = blockIdx.x >> 2;
    int o = (blockIdx.x & 3) + 1;
    int t = threadIdx.x;             // 256 threads, 147 active
    double acc = 0.0;
    if (t < 147) {
        int c = t / 49;
        int k = t - c * 49;
        int ky = k / 7, kx = k - ky * 7;
        double w = (double)convw[o * 147 + t];
        const double* base = rcs + ((size_t)(b * 3 + c) * 512) * 7 + kx;
        double s = 0.0;
        for (int oy = 0; oy < 256; ++oy) {
            int iy = 2 * oy + ky - 3;
            if ((unsigned)iy < 512u) s += base[(size_t)iy * 7];
        }
        acc = w * s;
    }
    __shared__ double red[256];
    red[t] = acc;
    __syncthreads();
    for (int s2 = 128; s2 > 0; s2 >>= 1) {
        if (t < s2) red[t] += red[t + s2];
        __syncthreads();
    }
    if (t == 0) partial[blockIdx.x] = red[0];
}

// ---------------- K3: GL conv (f64) -> crisp + fuzzed bin codes ----------------
__global__ void k3_gl(const double* __restrict__ imga, const float* __restrict__ weight,
                      uchar4* __restrict__ codes) {
    __shared__ double xv[101];
    for (int i = threadIdx.x; i < 101; i += 256) {
        double d = (double)i / 100.0;
        xv[i] = (double)(float)(10.0 * d * d * d);
    }
    __syncthreads();
    int idx = blockIdx.x * 256 + threadIdx.x;
    int xo = idx & 511;
    int yo = (idx >> 9) & 511;
    int b  = idx >> 18;
    const double* im = imga + (size_t)b * SP2;
    double GL = (double)weight[0];
    double a1 = GL * 4.0, a2 = -a1 / 8.0, a3 = -a1 / 16.0;
    auto g = [&](int y, int x) -> double {
        if ((unsigned)y >= 512u || (unsigned)x >= 512u) return 0.0;
        return im[y * 512 + x];
    };
    double v = a1 * g(yo, xo)
             + a2 * (g(yo - 1, xo) + g(yo, xo - 1) + g(yo, xo + 1) + g(yo + 1, xo))
             + a3 * (g(yo - 2, xo) + g(yo - 1, xo - 1) + g(yo - 1, xo + 1) + g(yo, xo - 2)
                   + g(yo, xo + 2) + g(yo + 1, xo - 1) + g(yo + 1, xo + 1) + g(yo + 2, xo));
    double t = fabs(v);
    auto classify = [&](double u) -> int {
        if (u < 1e-6) return 255;
        if (u > xv[100]) return 101;
        int lo = 0, hi = 100;
        while (lo < hi) { int mid = (lo + hi) >> 1; if (u <= xv[mid]) hi = mid; else lo = mid + 1; }
        return lo;
    };
    const double EPS = 6e-7;
    int cM = classify(t);
    int cA = classify(t - EPS);
    int cB = classify(t + EPS);
    codes[idx] = make_uchar4((unsigned char)cM, (unsigned char)cA, (unsigned char)cB, 0);
}

// ---------------- K4: per-batch crisp-code histogram (512 blocks, low atomic pressure) --------
__global__ void k4_hist(const uchar4* __restrict__ codes, int* __restrict__ ghist) {
    int b = blockIdx.y;
    __shared__ int h[102];
    for (int i = threadIdx.x; i < 102; i += 256) h[i] = 0;
    __syncthreads();
    const uchar4* cb = codes + (size_t)b * SP2;
    for (int p = blockIdx.x * 256 + threadIdx.x; p < SP2; p += 64 * 256) {
        int c = cb[p].x;
        if (c != 255) atomicAdd(&h[c], 1);
    }
    __syncthreads();
    for (int i = threadIdx.x; i < 102; i += 256)
        if (h[i]) atomicAdd(&ghist[b * 102 + i], h[i]);
}

// ---------------- K5: targets -> argmin with near-tie hedge (LDS, 1 block/batch) ------------
__global__ void k5_thr(const int* __restrict__ ghist, const double* __restrict__ partial,
                       const float* __restrict__ bn_gamma, const float* __restrict__ bn_beta,
                       const float* __restrict__ bn_mean, const float* __restrict__ bn_var,
                       int* __restrict__ thrLo, int* __restrict__ thrHi) {
    int b = blockIdx.x;
    int t = threadIdx.x;            // 128 threads
    __shared__ int    hS[102];
    __shared__ int    cumI[101];
    __shared__ double pct[101];
    __shared__ double ps[4];
    __shared__ int    allS;
    if (t < 102) hS[t] = ghist[b * 102 + t];
    __syncthreads();
    if (t == 0) {
        int all = 0;
        for (int k = 0; k < 102; ++k) all += hS[k];
        allS = all;
        int cum = 0;
        for (int k = 0; k < 101; ++k) { cum += hS[k]; cumI[k] = cum; }
    }
    __syncthreads();
    double alld = (double)allS;
    if (t < 101) pct[t] = (double)cumI[t] / alld;
    if (t < 4) {
        int o = t + 1;
        double s = partial[b * 4 + t];
        double m = s / 65536.0;
        double scale = (double)bn_gamma[o] / sqrt((double)bn_var[o] + 1e-5);
        double val = (m - (double)bn_mean[o]) * scale + (double)bn_beta[o];
        const double base[4] = {0.2, 0.4, 0.6, 0.8};
        ps[t] = base[t] + 0.05 * tanh(val);
    }
    __syncthreads();
    if (t == 0) {
        for (int i = 0; i < 4; ++i)
            for (int j = i + 1; j < 4; ++j)
                if (ps[j] < ps[i]) { double tp = ps[i]; ps[i] = ps[j]; ps[j] = tp; }
    }
    __syncthreads();
    if (t < 4) {
        const double EPS_TIE = 1.2e-7;
        double target = ps[t];
        double best = 1e300; int bi = 0;
        for (int k = 0; k < 101; ++k) {
            double z = fabs(pct[k] - target);
            if (z < best) { best = z; bi = k; }   // strict < => first occurrence
        }
        int lo = bi, hi = bi;
        for (int k = 0; k < 101; ++k) {
            double z = fabs(pct[k] - target);
            if (z <= best + EPS_TIE) { if (k < lo) lo = k; if (k > hi) hi = k; }
        }
        int cnt = cumI[hi] - cumI[lo];
        if (cnt > 2) { lo = bi; hi = bi; }
        thrLo[b * 4 + t] = lo;
        thrHi[b * 4 + t] = hi;
    }
}

// ---------------- K6: quarter-unit band mask (u8, values 0..4) ----------------
__global__ void k6_mask(const uchar4* __restrict__ codes, const int* __restrict__ thrLo,
                        const int* __restrict__ thrHi, unsigned char* __restrict__ mq) {
    int idx = blockIdx.x * 256 + threadIdx.x;
    int b = idx >> 18;
    int sp = idx & (SP2 - 1);
    uchar4 cd = codes[idx];
    const int* tL = thrLo + b * 4;
    const int* tH = thrHi + b * 4;
    int w0 = 0, w1 = 0, w2 = 0, w3 = 0, w4 = 0;
    int cand[2] = {cd.y, cd.z};
    #pragma unroll
    for (int ci = 0; ci < 2; ++ci) {
        int c = cand[ci];
        if (c == 255) continue;
        #pragma unroll
        for (int ti = 0; ti < 2; ++ti) {
            const int* t = ti ? tH : tL;
            if (c <= t[0]) ++w0;
            else if (c <= t[1]) ++w1;
            else if (c <= t[2]) ++w2;
            else if (c <= t[3]) ++w3;
            else ++w4;
        }
    }
    unsigned char* mb = mq + (size_t)b * 5 * SP2 + sp;
    mb[0]           = (unsigned char)w0;
    mb[SP2]         = (unsigned char)w1;
    mb[2 * SP2]     = (unsigned char)w2;
    mb[3 * SP2]     = (unsigned char)w3;
    mb[4 * SP2]     = (unsigned char)w4;
}

// ---------------- K7a: horizontal 17-tap triangle via sliding box9∘box9, 8 outputs/thread ----
__global__ void k7a(const unsigned char* __restrict__ q, unsigned short* __restrict__ out) {
    int tid = blockIdx.x * 256 + threadIdx.x;   // 20480 rows x 64 lanes
    int lane = tid & 63;
    int row  = tid >> 6;
    int x0 = lane * 8;
    const uint2* r8 = (const uint2*)(q + (size_t)row * 512);
    uint2 cL = (lane > 0)  ? r8[lane - 1] : make_uint2(0u, 0u);
    uint2 cM = r8[lane];
    uint2 cR = (lane < 63) ? r8[lane + 1] : make_uint2(0u, 0u);
    int v[24];
    auto unpack = [](uint2 c, int* dst) {
        dst[0] = c.x & 255; dst[1] = (c.x >> 8) & 255; dst[2] = (c.x >> 16) & 255; dst[3] = (c.x >> 24) & 255;
        dst[4] = c.y & 255; dst[5] = (c.y >> 8) & 255; dst[6] = (c.y >> 16) & 255; dst[7] = (c.y >> 24) & 255;
    };
    unpack(cL, v); unpack(cM, v + 8); unpack(cR, v + 16);
    // box9 at j = x0-4+k  covers v[k..k+8]   (v[0] = in[x0-8])
    int b[16];
    int s = 0;
    #pragma unroll
    for (int i = 0; i < 9; ++i) s += v[i];
    b[0] = s;
    #pragma unroll
    for (int k = 1; k < 16; ++k) { s += v[k + 8] - v[k - 1]; b[k] = s; }
    if (lane == 0)  { b[0] = 0; b[1] = 0; b[2] = 0; b[3] = 0; }       // j < 0
    if (lane == 63) { b[12] = 0; b[13] = 0; b[14] = 0; b[15] = 0; }   // j > 511
    // triangle at x0+i sums b[i..i+8]
    int t = 0;
    #pragma unroll
    for (int i = 0; i < 9; ++i) t += b[i];
    unsigned short o[8];
    o[0] = (unsigned short)t;
    #pragma unroll
    for (int i = 1; i < 8; ++i) { t += b[i + 8] - b[i - 1]; o[i] = (unsigned short)t; }
    uint4 pk;
    pk.x = (unsigned)o[0] | ((unsigned)o[1] << 16);
    pk.y = (unsigned)o[2] | ((unsigned)o[3] << 16);
    pk.z = (unsigned)o[4] | ((unsigned)o[5] << 16);
    pk.w = (unsigned)o[6] | ((unsigned)o[7] << 16);
    *(uint4*)(out + (size_t)row * 512 + x0) = pk;
}

// ---------------- K7b: vertical 17-tap triangle, sliding, 8 y-outputs/thread, XCD-swizzled ---
__global__ void k7b(const unsigned short* __restrict__ in, unsigned short* __restrict__ out) {
    int blk = (blockIdx.x & 7) * 640 + (blockIdx.x >> 3);   // bijective, nwg=5120
    int strip = blk & 1;
    int g     = (blk >> 1) & 63;
    int ch    = blk >> 7;
    int x  = strip * 256 + threadIdx.x;
    int y0 = g * 8;
    const unsigned short* cp = in + (size_t)ch * SP2;
    int v[24];
    #pragma unroll
    for (int i = 0; i < 24; ++i) {
        int iy = y0 - 8 + i;
        v[i] = ((unsigned)iy < 512u) ? (int)cp[iy * 512 + x] : 0;
    }
    int b[16];
    int s = 0;
    #pragma unroll
    for (int i = 0; i < 9; ++i) s += v[i];
    b[0] = s;
    #pragma unroll
    for (int k = 1; k < 16; ++k) { s += v[k + 8] - v[k - 1]; b[k] = s; }
    if (g == 0)  { b[0] = 0; b[1] = 0; b[2] = 0; b[3] = 0; }
    if (g == 63) { b[12] = 0; b[13] = 0; b[14] = 0; b[15] = 0; }
    int t = 0;
    #pragma unroll
    for (int i = 0; i < 9; ++i) t += b[i];
    unsigned short* op = out + (size_t)ch * SP2 + x;
    op[(size_t)y0 * 512] = (unsigned short)t;
    #pragma unroll
    for (int i = 1; i < 8; ++i) {
        t += b[i + 8] - b[i - 1];
        op[(size_t)(y0 + i) * 512] = (unsigned short)t;
    }
}

// ---------------- K7c: horizontal 9-tap stride-2, sliding, 4 outputs/thread ----------------
__global__ void k7c(const unsigned short* __restrict__ in, float* __restrict__ out) {
    int tid = blockIdx.x * 256 + threadIdx.x;   // 20480 rows x 64 lanes
    int lane = tid & 63;
    int row  = tid >> 6;
    int ox0 = lane * 4;
    const unsigned short* r = in + (size_t)row * 512;
    int v[15];
    #pragma unroll
    for (int i = 0; i < 15; ++i) {
        int ix = 2 * ox0 - 4 + i;
        v[i] = ((unsigned)ix < 512u) ? (int)r[ix] : 0;
    }
    int s = 0;
    #pragma unroll
    for (int i = 0; i < 9; ++i) s += v[i];
    float o[4];
    o[0] = (float)s;
    #pragma unroll
    for (int i = 1; i < 4; ++i) {
        s += v[2 * i + 7] + v[2 * i + 8] - v[2 * i - 2] - v[2 * i - 1];
        o[i] = (float)s;
    }
    *(float4*)(out + (size_t)row * 256 + ox0) = make_float4(o[0], o[1], o[2], o[3]);
}

// ---------------- K7d: vertical 9-tap stride-2, XCD-swizzled; per-block min/max partials -----
__global__ void k7d(const float* __restrict__ in, float* __restrict__ out,
                    float* __restrict__ pmn, float* __restrict__ pmx) {
    int w = (blockIdx.x & 7) * 1280 + (blockIdx.x >> 3);   // bijective, nwg=10240
    int idx = w * 256 + threadIdx.x;            // [40][256][256]; block = one row of one ch
    int xo = idx & 255;
    int y  = (idx >> 8) & 255;
    int ch = idx >> 16;
    const float* cp = in + (size_t)ch * 131072;
    int yb = 2 * y - 4;
    float s = 0.f;
    #pragma unroll
    for (int d = 0; d < 9; ++d) {
        int iy = yb + d;
        if ((unsigned)iy < 512u) s += cp[iy * 256 + xo];
    }
    float val = s / 2125764.0f;   // 4 * 81^3
    out[idx] = val;
    __shared__ float smn[256], smx[256];
    smn[threadIdx.x] = val; smx[threadIdx.x] = val;
    __syncthreads();
    for (int st = 128; st > 0; st >>= 1) {
        if (threadIdx.x < st) {
            smn[threadIdx.x] = fminf(smn[threadIdx.x], smn[threadIdx.x + st]);
            smx[threadIdx.x] = fmaxf(smx[threadIdx.x], smx[threadIdx.x + st]);
        }
        __syncthreads();
    }
    if (threadIdx.x == 0) { pmn[w] = smn[0]; pmx[w] = smx[0]; }
}

// ---------------- K8b: reduce 256 partials per channel (atomic-free) ----------------
__global__ void k8b(const float* __restrict__ pmn, const float* __restrict__ pmx,
                    float* __restrict__ mn, float* __restrict__ mx) {
    int ch = blockIdx.x;
    __shared__ float smn[256], smx[256];
    smn[threadIdx.x] = pmn[ch * 256 + threadIdx.x];
    smx[threadIdx.x] = pmx[ch * 256 + threadIdx.x];
    __syncthreads();
    for (int st = 128; st > 0; st >>= 1) {
        if (threadIdx.x < st) {
            smn[threadIdx.x] = fminf(smn[threadIdx.x], smn[threadIdx.x + st]);
            smx[threadIdx.x] = fmaxf(smx[threadIdx.x], smx[threadIdx.x + st]);
        }
        __syncthreads();
    }
    if (threadIdx.x == 0) { mn[ch] = smn[0]; mx[ch] = smx[0]; }
}

__global__ void k9_norm(float* __restrict__ o, const float* __restrict__ mn,
                        const float* __restrict__ mx) {
    int idx = blockIdx.x * 256 + threadIdx.x;
    int ch = idx >> 16;
    float a = mn[ch];
    o[idx] = (o[idx] - a) / (mx[ch] - a);
}

extern "C" void kernel_launch(void* const* d_in, const int* in_sizes, int n_in,
                              void* d_out, int out_size, void* d_ws, size_t ws_size,
                              hipStream_t stream) {
    const float* x      = (const float*)d_in[0];
    const float* weight = (const float*)d_in[1];
    const float* conv_w = (const float*)d_in[2];
    const float* bn_g   = (const float*)d_in[3];
    const float* bn_b   = (const float*)d_in[4];
    const float* bn_m   = (const float*)d_in[5];
    const float* bn_v   = (const float*)d_in[6];
    float* out = (float*)d_out;
    float* ws  = (float*)d_ws;

    double* imga   = (double*)ws;
    float*  pooled = ws + POOLF;
    uchar4* codes  = (uchar4*)(ws + POOLF);            // overlaps pooled; written after K2a
    unsigned char* maskq = (unsigned char*)(ws + MASKQF);
    double* rcs    = (double*)(ws + TRIHF);            // dead before k7a writes triH
    unsigned short* triH = (unsigned short*)(ws + TRIHF);
    unsigned short* triV = (unsigned short*)(ws + TRIVF);
    float*  h2buf  = ws;                               // overlaps imga/pooled (dead by K7c)
    double* partial = (double*)(ws + TAILF);           // 32 doubles
    int*    thrLo   = (int*)(ws + TAILF + 4096);
    int*    thrHi   = thrLo + 32;
    int*    ghist   = thrHi + 32;
    float*  pmn     = (float*)(ghist + 816);           // 10240
    float*  pmx     = pmn + 10240;                     // 10240
    float*  mn      = pmx + 10240;                     // 40
    float*  mx      = mn + 40;                         // 40

    hipMemsetAsync(ghist, 0, 816 * sizeof(int), stream);

    k1_pool3  <<<8192, 256, 0, stream>>>(x, pooled, imga);
    k2a       <<<12288, 256, 0, stream>>>(pooled, rcs);
    k2b       <<<32, 256, 0, stream>>>(rcs, conv_w, partial);
    k3_gl     <<<8192, 256, 0, stream>>>(imga, weight, codes);
    k4_hist   <<<dim3(64, B), 256, 0, stream>>>(codes, ghist);
    k5_thr    <<<B, 128, 0, stream>>>(ghist, partial, bn_g, bn_b, bn_m, bn_v, thrLo, thrHi);
    k6_mask   <<<8192, 256, 0, stream>>>(codes, thrLo, thrHi, maskq);
    k7a       <<<5120, 256, 0, stream>>>(maskq, triH);
    k7b       <<<5120, 256, 0, stream>>>(triH, triV);
    k7c       <<<5120, 256, 0, stream>>>(triV, h2buf);
    k7d       <<<10240, 256, 0, stream>>>(h2buf, out, pmn, pmx);
    k8b       <<<40, 256, 0, stream>>>(pmn, pmx, mn, mx);
    k9_norm   <<<10240, 256, 0, stream>>>(out, mn, mx);
}

// Round 13
// 196.528 us; speedup vs baseline: 2.5128x; 1.2401x over previous
//
#include <hip/hip_runtime.h>
#include <math.h>

// No FMA contraction: decision path rounds every op individually.
#pragma clang fp contract(off)

#define B 8
#define SP2 262144   // 512*512
#define SP3 65536    // 256*256

// ws float-indexed layout (~84 MB):
//  [0, 4194304)            imga f64 [8,512,512]        (K1->K3)
//  [4194304, 10485760)     pooled f32 [8,3,512,512]    (K1->K2a)
//  [4194304, 6291456)      codes uchar4 [8,512,512]    (K3 after K2a; ->K6)
//  [6291456, 8912896)      maskq u8 [8,5,512,512]      (K6 -> K7a)
//  [10485760, 15728640)    tri_h u16 [40,512,512]      (K7a -> K7b); rcs f64 [24,512,7] K2a->K2b
//  [15728640, 20971520)    tri_v u16 [40,512,512]      (K7b -> K7c)
//  [0, 5242880)            h2buf f32 [40,512,256]      (K7c -> K7d; imga/pooled dead)
//  [20971520, ...)         tail: partial 32 dbl | thrLo 32 | thrHi 32 | ghist 816 |
//                                pmn 10240 f | pmx 10240 f | mn 40 f | mx 40 f
#define POOLF  4194304
#define MASKQF 6291456
#define TRIHF  10485760
#define TRIVF  15728640
#define TAILF  20971520

// ---------------- K1: 3x3 s2 avgpool (f64) + channel mean ----------------
__global__ void k1_pool3(const float* __restrict__ x, float* __restrict__ pooled,
                         double* __restrict__ imga) {
    int idx = blockIdx.x * 256 + threadIdx.x;
    int xo = idx & 511;
    int yo = (idx >> 9) & 511;
    int b  = idx >> 18;
    int y0 = 2 * yo - 1, x0 = 2 * xo - 1;
    double pv[3];
    for (int c = 0; c < 3; ++c) {
        const float* p = x + ((size_t)(b * 3 + c)) * 1048576;
        double s = 0.0;
        #pragma unroll
        for (int dy = 0; dy < 3; ++dy) {
            int iy = y0 + dy;
            if ((unsigned)iy >= 1024u) continue;
            const float* row = p + (size_t)iy * 1024;
            #pragma unroll
            for (int dx = 0; dx < 3; ++dx) {
                int ix = x0 + dx;
                if ((unsigned)ix < 1024u) s += (double)row[ix];
            }
        }
        pv[c] = s / 9.0;
        pooled[((size_t)(b * 3 + c)) * SP2 + (idx & (SP2 - 1))] = (float)pv[c];
    }
    imga[idx] = ((pv[0] + pv[1]) + pv[2]) / 3.0;
}

// ---------------- K2a: per-(b,c,row) column-sublattice sums for the 7 kx offsets --------------
__global__ void k2a(const float* __restrict__ pooled, double* __restrict__ rcs) {
    int blk = blockIdx.x;            // (b*3+c)*512 + iy,  12288 blocks
    int iy = blk & 511;
    int bc = blk >> 9;
    const float* row = pooled + (size_t)bc * SP2 + iy * 512;
    double v[7] = {0, 0, 0, 0, 0, 0, 0};
    for (int ix = threadIdx.x; ix < 512; ix += 256) {
        double pv = (double)row[ix];
        #pragma unroll
        for (int kx = 0; kx < 7; ++kx) {
            int d = ix - (kx - 3);
            if (d >= 0 && d < 512 && !(d & 1)) v[kx] += pv;
        }
    }
    __shared__ double red[7][256];
    #pragma unroll
    for (int kx = 0; kx < 7; ++kx) red[kx][threadIdx.x] = v[kx];
    __syncthreads();
    for (int s = 128; s > 0; s >>= 1) {
        if (threadIdx.x < s) {
            #pragma unroll
            for (int kx = 0; kx < 7; ++kx)
                red[kx][threadIdx.x] += red[kx][threadIdx.x + s];
        }
        __syncthreads();
    }
    if (threadIdx.x < 7) rcs[(size_t)blk * 7 + threadIdx.x] = red[threadIdx.x][0];
}

// ---------------- K2b: combine -> conv spatial sum per (b, o=1..4) ----------------
// Parallel over oy (256 threads all active); taps looped inside (L2-resident loads).
__global__ void k2b(const double* __restrict__ rcs, const float* __restrict__ convw,
                    double* __restrict__ partial) {
    int b = blockIdx.x >> 2;
    int o = (blockIdx.x & 3) + 1;
    int t = threadIdx.x;             // t = oy in [0,256)
    double acc = 0.0;
    #pragma unroll 7
    for (int tap = 0; tap < 147; ++tap) {
        int c = tap / 49;
        int k = tap - c * 49;
        int ky = k / 7, kx = k - ky * 7;
        int iy = 2 * t + ky - 3;
        if ((unsigned)iy < 512u) {
            double w = (double)convw[o * 147 + tap];   // uniform -> scalar load
            acc += w * rcs[((size_t)(b * 3 + c) * 512 + iy) * 7 + kx];
        }
    }
    __shared__ double red[256];
    red[t] = acc;
    __syncthreads();
    for (int s2 = 128; s2 > 0; s2 >>= 1) {
        if (t < s2) red[t] += red[t + s2];
        __syncthreads();
    }
    if (t == 0) partial[blockIdx.x] = red[0];
}

// ---------------- K3: GL conv (f64) -> crisp + fuzzed bin codes ----------------
__global__ void k3_gl(const double* __restrict__ imga, const float* __restrict__ weight,
                      uchar4* __restrict__ codes) {
    __shared__ double xv[101];
    for (int i = threadIdx.x; i < 101; i += 256) {
        double d = (double)i / 100.0;
        xv[i] = (double)(float)(10.0 * d * d * d);
    }
    __syncthreads();
    int idx = blockIdx.x * 256 + threadIdx.x;
    int xo = idx & 511;
    int yo = (idx >> 9) & 511;
    int b  = idx >> 18;
    const double* im = imga + (size_t)b * SP2;
    double GL = (double)weight[0];
    double a1 = GL * 4.0, a2 = -a1 / 8.0, a3 = -a1 / 16.0;
    auto g = [&](int y, int x) -> double {
        if ((unsigned)y >= 512u || (unsigned)x >= 512u) return 0.0;
        return im[y * 512 + x];
    };
    double v = a1 * g(yo, xo)
             + a2 * (g(yo - 1, xo) + g(yo, xo - 1) + g(yo, xo + 1) + g(yo + 1, xo))
             + a3 * (g(yo - 2, xo) + g(yo - 1, xo - 1) + g(yo - 1, xo + 1) + g(yo, xo - 2)
                   + g(yo, xo + 2) + g(yo + 1, xo - 1) + g(yo + 1, xo + 1) + g(yo + 2, xo));
    double t = fabs(v);
    auto classify = [&](double u) -> int {
        if (u < 1e-6) return 255;
        if (u > xv[100]) return 101;
        int lo = 0, hi = 100;
        while (lo < hi) { int mid = (lo + hi) >> 1; if (u <= xv[mid]) hi = mid; else lo = mid + 1; }
        return lo;
    };
    const double EPS = 6e-7;
    int cM = classify(t);
    int cA = classify(t - EPS);
    int cB = classify(t + EPS);
    codes[idx] = make_uchar4((unsigned char)cM, (unsigned char)cA, (unsigned char)cB, 0);
}

// ---------------- K4: per-batch crisp-code histogram (512 blocks, low atomic pressure) --------
__global__ void k4_hist(const uchar4* __restrict__ codes, int* __restrict__ ghist) {
    int b = blockIdx.y;
    __shared__ int h[102];
    for (int i = threadIdx.x; i < 102; i += 256) h[i] = 0;
    __syncthreads();
    const uchar4* cb = codes + (size_t)b * SP2;
    for (int p = blockIdx.x * 256 + threadIdx.x; p < SP2; p += 64 * 256) {
        int c = cb[p].x;
        if (c != 255) atomicAdd(&h[c], 1);
    }
    __syncthreads();
    for (int i = threadIdx.x; i < 102; i += 256)
        if (h[i]) atomicAdd(&ghist[b * 102 + i], h[i]);
}

// ---------------- K5: targets -> argmin with near-tie hedge (LDS, 1 block/batch) ------------
__global__ void k5_thr(const int* __restrict__ ghist, const double* __restrict__ partial,
                       const float* __restrict__ bn_gamma, const float* __restrict__ bn_beta,
                       const float* __restrict__ bn_mean, const float* __restrict__ bn_var,
                       int* __restrict__ thrLo, int* __restrict__ thrHi) {
    int b = blockIdx.x;
    int t = threadIdx.x;            // 128 threads
    __shared__ int    hS[102];
    __shared__ int    cumI[101];
    __shared__ double pct[101];
    __shared__ double ps[4];
    __shared__ int    allS;
    if (t < 102) hS[t] = ghist[b * 102 + t];
    __syncthreads();
    if (t == 0) {
        int all = 0;
        for (int k = 0; k < 102; ++k) all += hS[k];
        allS = all;
        int cum = 0;
        for (int k = 0; k < 101; ++k) { cum += hS[k]; cumI[k] = cum; }
    }
    __syncthreads();
    double alld = (double)allS;
    if (t < 101) pct[t] = (double)cumI[t] / alld;
    if (t < 4) {
        int o = t + 1;
        double s = partial[b * 4 + t];
        double m = s / 65536.0;
        double scale = (double)bn_gamma[o] / sqrt((double)bn_var[o] + 1e-5);
        double val = (m - (double)bn_mean[o]) * scale + (double)bn_beta[o];
        const double base[4] = {0.2, 0.4, 0.6, 0.8};
        ps[t] = base[t] + 0.05 * tanh(val);
    }
    __syncthreads();
    if (t == 0) {
        for (int i = 0; i < 4; ++i)
            for (int j = i + 1; j < 4; ++j)
                if (ps[j] < ps[i]) { double tp = ps[i]; ps[i] = ps[j]; ps[j] = tp; }
    }
    __syncthreads();
    if (t < 4) {
        const double EPS_TIE = 1.2e-7;
        double target = ps[t];
        double best = 1e300; int bi = 0;
        for (int k = 0; k < 101; ++k) {
            double z = fabs(pct[k] - target);
            if (z < best) { best = z; bi = k; }   // strict < => first occurrence
        }
        int lo = bi, hi = bi;
        for (int k = 0; k < 101; ++k) {
            double z = fabs(pct[k] - target);
            if (z <= best + EPS_TIE) { if (k < lo) lo = k; if (k > hi) hi = k; }
        }
        int cnt = cumI[hi] - cumI[lo];
        if (cnt > 2) { lo = bi; hi = bi; }
        thrLo[b * 4 + t] = lo;
        thrHi[b * 4 + t] = hi;
    }
}

// ---------------- K6: quarter-unit band mask (u8, values 0..4) ----------------
__global__ void k6_mask(const uchar4* __restrict__ codes, const int* __restrict__ thrLo,
                        const int* __restrict__ thrHi, unsigned char* __restrict__ mq) {
    int idx = blockIdx.x * 256 + threadIdx.x;
    int b = idx >> 18;
    int sp = idx & (SP2 - 1);
    uchar4 cd = codes[idx];
    const int* tL = thrLo + b * 4;
    const int* tH = thrHi + b * 4;
    int w0 = 0, w1 = 0, w2 = 0, w3 = 0, w4 = 0;
    int cand[2] = {cd.y, cd.z};
    #pragma unroll
    for (int ci = 0; ci < 2; ++ci) {
        int c = cand[ci];
        if (c == 255) continue;
        #pragma unroll
        for (int ti = 0; ti < 2; ++ti) {
            const int* t = ti ? tH : tL;
            if (c <= t[0]) ++w0;
            else if (c <= t[1]) ++w1;
            else if (c <= t[2]) ++w2;
            else if (c <= t[3]) ++w3;
            else ++w4;
        }
    }
    unsigned char* mb = mq + (size_t)b * 5 * SP2 + sp;
    mb[0]           = (unsigned char)w0;
    mb[SP2]         = (unsigned char)w1;
    mb[2 * SP2]     = (unsigned char)w2;
    mb[3 * SP2]     = (unsigned char)w3;
    mb[4 * SP2]     = (unsigned char)w4;
}

// ---------------- K7a: horizontal 17-tap triangle via sliding box9∘box9, 8 outputs/thread ----
__global__ void k7a(const unsigned char* __restrict__ q, unsigned short* __restrict__ out) {
    int tid = blockIdx.x * 256 + threadIdx.x;   // 20480 rows x 64 lanes
    int lane = tid & 63;
    int row  = tid >> 6;
    int x0 = lane * 8;
    const uint2* r8 = (const uint2*)(q + (size_t)row * 512);
    uint2 cL = (lane > 0)  ? r8[lane - 1] : make_uint2(0u, 0u);
    uint2 cM = r8[lane];
    uint2 cR = (lane < 63) ? r8[lane + 1] : make_uint2(0u, 0u);
    int v[24];
    auto unpack = [](uint2 c, int* dst) {
        dst[0] = c.x & 255; dst[1] = (c.x >> 8) & 255; dst[2] = (c.x >> 16) & 255; dst[3] = (c.x >> 24) & 255;
        dst[4] = c.y & 255; dst[5] = (c.y >> 8) & 255; dst[6] = (c.y >> 16) & 255; dst[7] = (c.y >> 24) & 255;
    };
    unpack(cL, v); unpack(cM, v + 8); unpack(cR, v + 16);
    int b[16];
    int s = 0;
    #pragma unroll
    for (int i = 0; i < 9; ++i) s += v[i];
    b[0] = s;
    #pragma unroll
    for (int k = 1; k < 16; ++k) { s += v[k + 8] - v[k - 1]; b[k] = s; }
    if (lane == 0)  { b[0] = 0; b[1] = 0; b[2] = 0; b[3] = 0; }
    if (lane == 63) { b[12] = 0; b[13] = 0; b[14] = 0; b[15] = 0; }
    int t = 0;
    #pragma unroll
    for (int i = 0; i < 9; ++i) t += b[i];
    unsigned short o[8];
    o[0] = (unsigned short)t;
    #pragma unroll
    for (int i = 1; i < 8; ++i) { t += b[i + 8] - b[i - 1]; o[i] = (unsigned short)t; }
    uint4 pk;
    pk.x = (unsigned)o[0] | ((unsigned)o[1] << 16);
    pk.y = (unsigned)o[2] | ((unsigned)o[3] << 16);
    pk.z = (unsigned)o[4] | ((unsigned)o[5] << 16);
    pk.w = (unsigned)o[6] | ((unsigned)o[7] << 16);
    *(uint4*)(out + (size_t)row * 512 + x0) = pk;
}

// ---------------- K7b: vertical 17-tap triangle, sliding, 8 y-outputs/thread, XCD-swizzled ---
__global__ void k7b(const unsigned short* __restrict__ in, unsigned short* __restrict__ out) {
    int blk = (blockIdx.x & 7) * 640 + (blockIdx.x >> 3);   // bijective, nwg=5120
    int strip = blk & 1;
    int g     = (blk >> 1) & 63;
    int ch    = blk >> 7;
    int x  = strip * 256 + threadIdx.x;
    int y0 = g * 8;
    const unsigned short* cp = in + (size_t)ch * SP2;
    int v[24];
    #pragma unroll
    for (int i = 0; i < 24; ++i) {
        int iy = y0 - 8 + i;
        v[i] = ((unsigned)iy < 512u) ? (int)cp[iy * 512 + x] : 0;
    }
    int b[16];
    int s = 0;
    #pragma unroll
    for (int i = 0; i < 9; ++i) s += v[i];
    b[0] = s;
    #pragma unroll
    for (int k = 1; k < 16; ++k) { s += v[k + 8] - v[k - 1]; b[k] = s; }
    if (g == 0)  { b[0] = 0; b[1] = 0; b[2] = 0; b[3] = 0; }
    if (g == 63) { b[12] = 0; b[13] = 0; b[14] = 0; b[15] = 0; }
    int t = 0;
    #pragma unroll
    for (int i = 0; i < 9; ++i) t += b[i];
    unsigned short* op = out + (size_t)ch * SP2 + x;
    op[(size_t)y0 * 512] = (unsigned short)t;
    #pragma unroll
    for (int i = 1; i < 8; ++i) {
        t += b[i + 8] - b[i - 1];
        op[(size_t)(y0 + i) * 512] = (unsigned short)t;
    }
}

// ---------------- K7c: horizontal 9-tap stride-2, sliding, 4 outputs/thread ----------------
__global__ void k7c(const unsigned short* __restrict__ in, float* __restrict__ out) {
    int tid = blockIdx.x * 256 + threadIdx.x;   // 20480 rows x 64 lanes
    int lane = tid & 63;
    int row  = tid >> 6;
    int ox0 = lane * 4;
    const unsigned short* r = in + (size_t)row * 512;
    int v[15];
    #pragma unroll
    for (int i = 0; i < 15; ++i) {
        int ix = 2 * ox0 - 4 + i;
        v[i] = ((unsigned)ix < 512u) ? (int)r[ix] : 0;
    }
    int s = 0;
    #pragma unroll
    for (int i = 0; i < 9; ++i) s += v[i];
    float o[4];
    o[0] = (float)s;
    #pragma unroll
    for (int i = 1; i < 4; ++i) {
        s += v[2 * i + 7] + v[2 * i + 8] - v[2 * i - 2] - v[2 * i - 1];
        o[i] = (float)s;
    }
    *(float4*)(out + (size_t)row * 256 + ox0) = make_float4(o[0], o[1], o[2], o[3]);
}

// ---------------- K7d: vertical 9-tap stride-2, XCD-swizzled; per-block min/max partials -----
__global__ void k7d(const float* __restrict__ in, float* __restrict__ out,
                    float* __restrict__ pmn, float* __restrict__ pmx) {
    int w = (blockIdx.x & 7) * 1280 + (blockIdx.x >> 3);   // bijective, nwg=10240
    int idx = w * 256 + threadIdx.x;            // [40][256][256]; block = one row of one ch
    int xo = idx & 255;
    int y  = (idx >> 8) & 255;
    int ch = idx >> 16;
    const float* cp = in + (size_t)ch * 131072;
    int yb = 2 * y - 4;
    float s = 0.f;
    #pragma unroll
    for (int d = 0; d < 9; ++d) {
        int iy = yb + d;
        if ((unsigned)iy < 512u) s += cp[iy * 256 + xo];
    }
    float val = s / 2125764.0f;   // 4 * 81^3
    out[idx] = val;
    __shared__ float smn[256], smx[256];
    smn[threadIdx.x] = val; smx[threadIdx.x] = val;
    __syncthreads();
    for (int st = 128; st > 0; st >>= 1) {
        if (threadIdx.x < st) {
            smn[threadIdx.x] = fminf(smn[threadIdx.x], smn[threadIdx.x + st]);
            smx[threadIdx.x] = fmaxf(smx[threadIdx.x], smx[threadIdx.x + st]);
        }
        __syncthreads();
    }
    if (threadIdx.x == 0) { pmn[w] = smn[0]; pmx[w] = smx[0]; }
}

// ---------------- K8b: reduce 256 partials per channel (atomic-free) ----------------
__global__ void k8b(const float* __restrict__ pmn, const float* __restrict__ pmx,
                    float* __restrict__ mn, float* __restrict__ mx) {
    int ch = blockIdx.x;
    __shared__ float smn[256], smx[256];
    smn[threadIdx.x] = pmn[ch * 256 + threadIdx.x];
    smx[threadIdx.x] = pmx[ch * 256 + threadIdx.x];
    __syncthreads();
    for (int st = 128; st > 0; st >>= 1) {
        if (threadIdx.x < st) {
            smn[threadIdx.x] = fminf(smn[threadIdx.x], smn[threadIdx.x + st]);
            smx[threadIdx.x] = fmaxf(smx[threadIdx.x], smx[threadIdx.x + st]);
        }
        __syncthreads();
    }
    if (threadIdx.x == 0) { mn[ch] = smn[0]; mx[ch] = smx[0]; }
}

__global__ void k9_norm(float* __restrict__ o, const float* __restrict__ mn,
                        const float* __restrict__ mx) {
    int idx = blockIdx.x * 256 + threadIdx.x;
    int ch = idx >> 16;
    float a = mn[ch];
    o[idx] = (o[idx] - a) / (mx[ch] - a);
}

extern "C" void kernel_launch(void* const* d_in, const int* in_sizes, int n_in,
                              void* d_out, int out_size, void* d_ws, size_t ws_size,
                              hipStream_t stream) {
    const float* x      = (const float*)d_in[0];
    const float* weight = (const float*)d_in[1];
    const float* conv_w = (const float*)d_in[2];
    const float* bn_g   = (const float*)d_in[3];
    const float* bn_b   = (const float*)d_in[4];
    const float* bn_m   = (const float*)d_in[5];
    const float* bn_v   = (const float*)d_in[6];
    float* out = (float*)d_out;
    float* ws  = (float*)d_ws;

    double* imga   = (double*)ws;
    float*  pooled = ws + POOLF;
    uchar4* codes  = (uchar4*)(ws + POOLF);            // overlaps pooled; written after K2a
    unsigned char* maskq = (unsigned char*)(ws + MASKQF);
    double* rcs    = (double*)(ws + TRIHF);            // dead before k7a writes triH
    unsigned short* triH = (unsigned short*)(ws + TRIHF);
    unsigned short* triV = (unsigned short*)(ws + TRIVF);
    float*  h2buf  = ws;                               // overlaps imga/pooled (dead by K7c)
    double* partial = (double*)(ws + TAILF);           // 32 doubles
    int*    thrLo   = (int*)(ws + TAILF + 4096);
    int*    thrHi   = thrLo + 32;
    int*    ghist   = thrHi + 32;
    float*  pmn     = (float*)(ghist + 816);           // 10240
    float*  pmx     = pmn + 10240;                     // 10240
    float*  mn      = pmx + 10240;                     // 40
    float*  mx      = mn + 40;                         // 40

    hipMemsetAsync(ghist, 0, 816 * sizeof(int), stream);

    k1_pool3  <<<8192, 256, 0, stream>>>(x, pooled, imga);
    k2a       <<<12288, 256, 0, stream>>>(pooled, rcs);
    k2b       <<<32, 256, 0, stream>>>(rcs, conv_w, partial);
    k3_gl     <<<8192, 256, 0, stream>>>(imga, weight, codes);
    k4_hist   <<<dim3(64, B), 256, 0, stream>>>(codes, ghist);
    k5_thr    <<<B, 128, 0, stream>>>(ghist, partial, bn_g, bn_b, bn_m, bn_v, thrLo, thrHi);
    k6_mask   <<<8192, 256, 0, stream>>>(codes, thrLo, thrHi, maskq);
    k7a       <<<5120, 256, 0, stream>>>(maskq, triH);
    k7b       <<<5120, 256, 0, stream>>>(triH, triV);
    k7c       <<<5120, 256, 0, stream>>>(triV, h2buf);
    k7d       <<<10240, 256, 0, stream>>>(h2buf, out, pmn, pmx);
    k8b       <<<40, 256, 0, stream>>>(pmn, pmx, mn, mx);
    k9_norm   <<<10240, 256, 0, stream>>>(out, mn, mx);
}

// Round 14
// 187.748 us; speedup vs baseline: 2.6303x; 1.0468x over previous
//
#include <hip/hip_runtime.h>
#include <math.h>

// No FMA contraction: decision path rounds every op individually.
#pragma clang fp contract(off)

#define B 8
#define SP2 262144   // 512*512
#define SP3 65536    // 256*256

// ws float-indexed layout (~84 MB):
//  [0, 4194304)            imga f64 [8,512,512]        (K1->K3)
//  [4194304, 10485760)     pooled f32 [8,3,512,512]    (K1->K2a)
//  [4194304, 6291456)      codes uchar4 [8,512,512]    (K3 after K2a; ->K6)
//  [6291456, 8912896)      maskq u8 [8,5,512,512]      (K6 -> K7a)
//  [10485760, 15728640)    tri_h u16 [40,512,512]      (K7a -> K7b); rcs f64 [24,512,7] K2a->K2b
//  [15728640, 20971520)    tri_v u16 [40,512,512]      (K7b -> K7c)
//  [0, 5242880)            h2buf f32 [40,512,256]      (K7c -> K7d; imga/pooled dead)
//  [20971520, ...)         tail: partial 32 dbl | thrLo 32 | thrHi 32 | ghist 816 |
//                                pmn 10240 f | pmx 10240 f | mn 40 f | mx 40 f
#define POOLF  4194304
#define MASKQF 6291456
#define TRIHF  10485760
#define TRIVF  15728640
#define TAILF  20971520

// ---------------- K1: 3x3 s2 avgpool (f64) + channel mean, 4 outputs/thread, float4 loads ----
__global__ void k1_pool3(const float* __restrict__ x, float* __restrict__ pooled,
                         double* __restrict__ imga) {
    int tid = blockIdx.x * 256 + threadIdx.x;   // [0, 8*512*128): (b, yo, quad)
    int q  = tid & 127;            // quad: outputs xo = 4q .. 4q+3
    int yo = (tid >> 7) & 511;
    int b  = tid >> 16;
    int xb = 8 * q;                // input col base; need cols xb-1 .. xb+7
    double pv[3][4];
    for (int c = 0; c < 3; ++c) {
        const float* p = x + ((size_t)(b * 3 + c)) * 1048576;
        // rows iy = 2*yo-1+dy; accumulate window sums in f64, dy-major
        double s0 = 0.0, s1 = 0.0, s2 = 0.0, s3 = 0.0;
        #pragma unroll
        for (int dy = 0; dy < 3; ++dy) {
            int iy = 2 * yo - 1 + dy;
            if ((unsigned)iy >= 1024u) continue;
            const float* row = p + (size_t)iy * 1024 + xb;
            float4 fM = *(const float4*)row;           // cols xb .. xb+3
            float4 fR = *(const float4*)(row + 4);     // cols xb+4 .. xb+7
            float  vm1 = (q > 0) ? row[-1] : 0.f;      // col xb-1 (zero-pad at q=0)
            // v[-1..7] = vm1, fM.xyzw, fR.xyzw
            s0 += (double)vm1  + (double)fM.x + (double)fM.y;   // cols -1,0,1
            s1 += (double)fM.y + (double)fM.z + (double)fM.w;   // cols 1,2,3
            s2 += (double)fM.w + (double)fR.x + (double)fR.y;   // cols 3,4,5
            s3 += (double)fR.y + (double)fR.z + (double)fR.w;   // cols 5,6,7
        }
        pv[c][0] = s0 / 9.0; pv[c][1] = s1 / 9.0; pv[c][2] = s2 / 9.0; pv[c][3] = s3 / 9.0;
        float4 st = make_float4((float)pv[c][0], (float)pv[c][1], (float)pv[c][2], (float)pv[c][3]);
        *(float4*)(pooled + ((size_t)(b * 3 + c)) * SP2 + yo * 512 + 4 * q) = st;
    }
    double* ia = imga + (size_t)b * SP2 + yo * 512 + 4 * q;
    #pragma unroll
    for (int k = 0; k < 4; ++k)
        ia[k] = ((pv[0][k] + pv[1][k]) + pv[2][k]) / 3.0;
}

// ---------------- K2a: per-(b,c,row) column-sublattice sums for the 7 kx offsets --------------
__global__ void k2a(const float* __restrict__ pooled, double* __restrict__ rcs) {
    int blk = blockIdx.x;            // (b*3+c)*512 + iy,  12288 blocks
    int iy = blk & 511;
    int bc = blk >> 9;
    const float* row = pooled + (size_t)bc * SP2 + iy * 512;
    double v[7] = {0, 0, 0, 0, 0, 0, 0};
    for (int ix = threadIdx.x; ix < 512; ix += 256) {
        double pv = (double)row[ix];
        #pragma unroll
        for (int kx = 0; kx < 7; ++kx) {
            int d = ix - (kx - 3);
            if (d >= 0 && d < 512 && !(d & 1)) v[kx] += pv;
        }
    }
    __shared__ double red[7][256];
    #pragma unroll
    for (int kx = 0; kx < 7; ++kx) red[kx][threadIdx.x] = v[kx];
    __syncthreads();
    for (int s = 128; s > 0; s >>= 1) {
        if (threadIdx.x < s) {
            #pragma unroll
            for (int kx = 0; kx < 7; ++kx)
                red[kx][threadIdx.x] += red[kx][threadIdx.x + s];
        }
        __syncthreads();
    }
    if (threadIdx.x < 7) rcs[(size_t)blk * 7 + threadIdx.x] = red[threadIdx.x][0];
}

// ---------------- K2b: combine -> conv spatial sum per (b, o=1..4), oy-parallel ---------------
__global__ void k2b(const double* __restrict__ rcs, const float* __restrict__ convw,
                    double* __restrict__ partial) {
    int b = blockIdx.x >> 2;
    int o = (blockIdx.x & 3) + 1;
    int t = threadIdx.x;             // t = oy in [0,256)
    double acc = 0.0;
    #pragma unroll 7
    for (int tap = 0; tap < 147; ++tap) {
        int c = tap / 49;
        int k = tap - c * 49;
        int ky = k / 7, kx = k - ky * 7;
        int iy = 2 * t + ky - 3;
        if ((unsigned)iy < 512u) {
            double w = (double)convw[o * 147 + tap];   // uniform -> scalar load
            acc += w * rcs[((size_t)(b * 3 + c) * 512 + iy) * 7 + kx];
        }
    }
    __shared__ double red[256];
    red[t] = acc;
    __syncthreads();
    for (int s2 = 128; s2 > 0; s2 >>= 1) {
        if (t < s2) red[t] += red[t + s2];
        __syncthreads();
    }
    if (t == 0) partial[blockIdx.x] = red[0];
}

// ---------------- K3: GL conv (f64) -> crisp + fuzzed bin codes ----------------
__global__ void k3_gl(const double* __restrict__ imga, const float* __restrict__ weight,
                      uchar4* __restrict__ codes) {
    __shared__ double xv[101];
    for (int i = threadIdx.x; i < 101; i += 256) {
        double d = (double)i / 100.0;
        xv[i] = (double)(float)(10.0 * d * d * d);
    }
    __syncthreads();
    int idx = blockIdx.x * 256 + threadIdx.x;
    int xo = idx & 511;
    int yo = (idx >> 9) & 511;
    int b  = idx >> 18;
    const double* im = imga + (size_t)b * SP2;
    double GL = (double)weight[0];
    double a1 = GL * 4.0, a2 = -a1 / 8.0, a3 = -a1 / 16.0;
    auto g = [&](int y, int x) -> double {
        if ((unsigned)y >= 512u || (unsigned)x >= 512u) return 0.0;
        return im[y * 512 + x];
    };
    double v = a1 * g(yo, xo)
             + a2 * (g(yo - 1, xo) + g(yo, xo - 1) + g(yo, xo + 1) + g(yo + 1, xo))
             + a3 * (g(yo - 2, xo) + g(yo - 1, xo - 1) + g(yo - 1, xo + 1) + g(yo, xo - 2)
                   + g(yo, xo + 2) + g(yo + 1, xo - 1) + g(yo + 1, xo + 1) + g(yo + 2, xo));
    double t = fabs(v);
    auto classify = [&](double u) -> int {
        if (u < 1e-6) return 255;
        if (u > xv[100]) return 101;
        int lo = 0, hi = 100;
        while (lo < hi) { int mid = (lo + hi) >> 1; if (u <= xv[mid]) hi = mid; else lo = mid + 1; }
        return lo;
    };
    const double EPS = 6e-7;
    int cM = classify(t);
    int cA = classify(t - EPS);
    int cB = classify(t + EPS);
    codes[idx] = make_uchar4((unsigned char)cM, (unsigned char)cA, (unsigned char)cB, 0);
}

// ---------------- K4: per-batch crisp-code histogram (512 blocks, low atomic pressure) --------
__global__ void k4_hist(const uchar4* __restrict__ codes, int* __restrict__ ghist) {
    int b = blockIdx.y;
    __shared__ int h[102];
    for (int i = threadIdx.x; i < 102; i += 256) h[i] = 0;
    __syncthreads();
    const uchar4* cb = codes + (size_t)b * SP2;
    for (int p = blockIdx.x * 256 + threadIdx.x; p < SP2; p += 64 * 256) {
        int c = cb[p].x;
        if (c != 255) atomicAdd(&h[c], 1);
    }
    __syncthreads();
    for (int i = threadIdx.x; i < 102; i += 256)
        if (h[i]) atomicAdd(&ghist[b * 102 + i], h[i]);
}

// ---------------- K5: targets -> argmin with near-tie hedge (LDS, 1 block/batch) ------------
__global__ void k5_thr(const int* __restrict__ ghist, const double* __restrict__ partial,
                       const float* __restrict__ bn_gamma, const float* __restrict__ bn_beta,
                       const float* __restrict__ bn_mean, const float* __restrict__ bn_var,
                       int* __restrict__ thrLo, int* __restrict__ thrHi) {
    int b = blockIdx.x;
    int t = threadIdx.x;            // 128 threads
    __shared__ int    hS[102];
    __shared__ int    cumI[101];
    __shared__ double pct[101];
    __shared__ double ps[4];
    __shared__ int    allS;
    if (t < 102) hS[t] = ghist[b * 102 + t];
    __syncthreads();
    if (t == 0) {
        int all = 0;
        for (int k = 0; k < 102; ++k) all += hS[k];
        allS = all;
        int cum = 0;
        for (int k = 0; k < 101; ++k) { cum += hS[k]; cumI[k] = cum; }
    }
    __syncthreads();
    double alld = (double)allS;
    if (t < 101) pct[t] = (double)cumI[t] / alld;
    if (t < 4) {
        int o = t + 1;
        double s = partial[b * 4 + t];
        double m = s / 65536.0;
        double scale = (double)bn_gamma[o] / sqrt((double)bn_var[o] + 1e-5);
        double val = (m - (double)bn_mean[o]) * scale + (double)bn_beta[o];
        const double base[4] = {0.2, 0.4, 0.6, 0.8};
        ps[t] = base[t] + 0.05 * tanh(val);
    }
    __syncthreads();
    if (t == 0) {
        for (int i = 0; i < 4; ++i)
            for (int j = i + 1; j < 4; ++j)
                if (ps[j] < ps[i]) { double tp = ps[i]; ps[i] = ps[j]; ps[j] = tp; }
    }
    __syncthreads();
    if (t < 4) {
        const double EPS_TIE = 1.2e-7;
        double target = ps[t];
        double best = 1e300; int bi = 0;
        for (int k = 0; k < 101; ++k) {
            double z = fabs(pct[k] - target);
            if (z < best) { best = z; bi = k; }   // strict < => first occurrence
        }
        int lo = bi, hi = bi;
        for (int k = 0; k < 101; ++k) {
            double z = fabs(pct[k] - target);
            if (z <= best + EPS_TIE) { if (k < lo) lo = k; if (k > hi) hi = k; }
        }
        int cnt = cumI[hi] - cumI[lo];
        if (cnt > 2) { lo = bi; hi = bi; }
        thrLo[b * 4 + t] = lo;
        thrHi[b * 4 + t] = hi;
    }
}

// ---------------- K6: quarter-unit band mask (u8, values 0..4) ----------------
__global__ void k6_mask(const uchar4* __restrict__ codes, const int* __restrict__ thrLo,
                        const int* __restrict__ thrHi, unsigned char* __restrict__ mq) {
    int idx = blockIdx.x * 256 + threadIdx.x;
    int b = idx >> 18;
    int sp = idx & (SP2 - 1);
    uchar4 cd = codes[idx];
    const int* tL = thrLo + b * 4;
    const int* tH = thrHi + b * 4;
    int w0 = 0, w1 = 0, w2 = 0, w3 = 0, w4 = 0;
    int cand[2] = {cd.y, cd.z};
    #pragma unroll
    for (int ci = 0; ci < 2; ++ci) {
        int c = cand[ci];
        if (c == 255) continue;
        #pragma unroll
        for (int ti = 0; ti < 2; ++ti) {
            const int* t = ti ? tH : tL;
            if (c <= t[0]) ++w0;
            else if (c <= t[1]) ++w1;
            else if (c <= t[2]) ++w2;
            else if (c <= t[3]) ++w3;
            else ++w4;
        }
    }
    unsigned char* mb = mq + (size_t)b * 5 * SP2 + sp;
    mb[0]           = (unsigned char)w0;
    mb[SP2]         = (unsigned char)w1;
    mb[2 * SP2]     = (unsigned char)w2;
    mb[3 * SP2]     = (unsigned char)w3;
    mb[4 * SP2]     = (unsigned char)w4;
}

// ---------------- K7a: horizontal 17-tap triangle via sliding box9∘box9, 8 outputs/thread ----
__global__ void k7a(const unsigned char* __restrict__ q, unsigned short* __restrict__ out) {
    int tid = blockIdx.x * 256 + threadIdx.x;   // 20480 rows x 64 lanes
    int lane = tid & 63;
    int row  = tid >> 6;
    int x0 = lane * 8;
    const uint2* r8 = (const uint2*)(q + (size_t)row * 512);
    uint2 cL = (lane > 0)  ? r8[lane - 1] : make_uint2(0u, 0u);
    uint2 cM = r8[lane];
    uint2 cR = (lane < 63) ? r8[lane + 1] : make_uint2(0u, 0u);
    int v[24];
    auto unpack = [](uint2 c, int* dst) {
        dst[0] = c.x & 255; dst[1] = (c.x >> 8) & 255; dst[2] = (c.x >> 16) & 255; dst[3] = (c.x >> 24) & 255;
        dst[4] = c.y & 255; dst[5] = (c.y >> 8) & 255; dst[6] = (c.y >> 16) & 255; dst[7] = (c.y >> 24) & 255;
    };
    unpack(cL, v); unpack(cM, v + 8); unpack(cR, v + 16);
    int b[16];
    int s = 0;
    #pragma unroll
    for (int i = 0; i < 9; ++i) s += v[i];
    b[0] = s;
    #pragma unroll
    for (int k = 1; k < 16; ++k) { s += v[k + 8] - v[k - 1]; b[k] = s; }
    if (lane == 0)  { b[0] = 0; b[1] = 0; b[2] = 0; b[3] = 0; }
    if (lane == 63) { b[12] = 0; b[13] = 0; b[14] = 0; b[15] = 0; }
    int t = 0;
    #pragma unroll
    for (int i = 0; i < 9; ++i) t += b[i];
    unsigned short o[8];
    o[0] = (unsigned short)t;
    #pragma unroll
    for (int i = 1; i < 8; ++i) { t += b[i + 8] - b[i - 1]; o[i] = (unsigned short)t; }
    uint4 pk;
    pk.x = (unsigned)o[0] | ((unsigned)o[1] << 16);
    pk.y = (unsigned)o[2] | ((unsigned)o[3] << 16);
    pk.z = (unsigned)o[4] | ((unsigned)o[5] << 16);
    pk.w = (unsigned)o[6] | ((unsigned)o[7] << 16);
    *(uint4*)(out + (size_t)row * 512 + x0) = pk;
}

// ---------------- K7b: vertical 17-tap triangle, sliding, 8 y-outputs/thread, XCD-swizzled ---
__global__ void k7b(const unsigned short* __restrict__ in, unsigned short* __restrict__ out) {
    int blk = (blockIdx.x & 7) * 640 + (blockIdx.x >> 3);   // bijective, nwg=5120
    int strip = blk & 1;
    int g     = (blk >> 1) & 63;
    int ch    = blk >> 7;
    int x  = strip * 256 + threadIdx.x;
    int y0 = g * 8;
    const unsigned short* cp = in + (size_t)ch * SP2;
    int v[24];
    #pragma unroll
    for (int i = 0; i < 24; ++i) {
        int iy = y0 - 8 + i;
        v[i] = ((unsigned)iy < 512u) ? (int)cp[iy * 512 + x] : 0;
    }
    int b[16];
    int s = 0;
    #pragma unroll
    for (int i = 0; i < 9; ++i) s += v[i];
    b[0] = s;
    #pragma unroll
    for (int k = 1; k < 16; ++k) { s += v[k + 8] - v[k - 1]; b[k] = s; }
    if (g == 0)  { b[0] = 0; b[1] = 0; b[2] = 0; b[3] = 0; }
    if (g == 63) { b[12] = 0; b[13] = 0; b[14] = 0; b[15] = 0; }
    int t = 0;
    #pragma unroll
    for (int i = 0; i < 9; ++i) t += b[i];
    unsigned short* op = out + (size_t)ch * SP2 + x;
    op[(size_t)y0 * 512] = (unsigned short)t;
    #pragma unroll
    for (int i = 1; i < 8; ++i) {
        t += b[i + 8] - b[i - 1];
        op[(size_t)(y0 + i) * 512] = (unsigned short)t;
    }
}

// ---------------- K7c: horizontal 9-tap stride-2, sliding, 4 outputs/thread ----------------
__global__ void k7c(const unsigned short* __restrict__ in, float* __restrict__ out) {
    int tid = blockIdx.x * 256 + threadIdx.x;   // 20480 rows x 64 lanes
    int lane = tid & 63;
    int row  = tid >> 6;
    int ox0 = lane * 4;
    const unsigned short* r = in + (size_t)row * 512;
    int v[15];
    #pragma unroll
    for (int i = 0; i < 15; ++i) {
        int ix = 2 * ox0 - 4 + i;
        v[i] = ((unsigned)ix < 512u) ? (int)r[ix] : 0;
    }
    int s = 0;
    #pragma unroll
    for (int i = 0; i < 9; ++i) s += v[i];
    float o[4];
    o[0] = (float)s;
    #pragma unroll
    for (int i = 1; i < 4; ++i) {
        s += v[2 * i + 7] + v[2 * i + 8] - v[2 * i - 2] - v[2 * i - 1];
        o[i] = (float)s;
    }
    *(float4*)(out + (size_t)row * 256 + ox0) = make_float4(o[0], o[1], o[2], o[3]);
}

// ---------------- K7d: vertical 9-tap stride-2, XCD-swizzled; per-block min/max partials -----
__global__ void k7d(const float* __restrict__ in, float* __restrict__ out,
                    float* __restrict__ pmn, float* __restrict__ pmx) {
    int w = (blockIdx.x & 7) * 1280 + (blockIdx.x >> 3);   // bijective, nwg=10240
    int idx = w * 256 + threadIdx.x;            // [40][256][256]; block = one row of one ch
    int xo = idx & 255;
    int y  = (idx >> 8) & 255;
    int ch = idx >> 16;
    const float* cp = in + (size_t)ch * 131072;
    int yb = 2 * y - 4;
    float s = 0.f;
    #pragma unroll
    for (int d = 0; d < 9; ++d) {
        int iy = yb + d;
        if ((unsigned)iy < 512u) s += cp[iy * 256 + xo];
    }
    float val = s / 2125764.0f;   // 4 * 81^3
    out[idx] = val;
    __shared__ float smn[256], smx[256];
    smn[threadIdx.x] = val; smx[threadIdx.x] = val;
    __syncthreads();
    for (int st = 128; st > 0; st >>= 1) {
        if (threadIdx.x < st) {
            smn[threadIdx.x] = fminf(smn[threadIdx.x], smn[threadIdx.x + st]);
            smx[threadIdx.x] = fmaxf(smx[threadIdx.x], smx[threadIdx.x + st]);
        }
        __syncthreads();
    }
    if (threadIdx.x == 0) { pmn[w] = smn[0]; pmx[w] = smx[0]; }
}

// ---------------- K8b: reduce 256 partials per channel (atomic-free) ----------------
__global__ void k8b(const float* __restrict__ pmn, const float* __restrict__ pmx,
                    float* __restrict__ mn, float* __restrict__ mx) {
    int ch = blockIdx.x;
    __shared__ float smn[256], smx[256];
    smn[threadIdx.x] = pmn[ch * 256 + threadIdx.x];
    smx[threadIdx.x] = pmx[ch * 256 + threadIdx.x];
    __syncthreads();
    for (int st = 128; st > 0; st >>= 1) {
        if (threadIdx.x < st) {
            smn[threadIdx.x] = fminf(smn[threadIdx.x], smn[threadIdx.x + st]);
            smx[threadIdx.x] = fmaxf(smx[threadIdx.x], smx[threadIdx.x + st]);
        }
        __syncthreads();
    }
    if (threadIdx.x == 0) { mn[ch] = smn[0]; mx[ch] = smx[0]; }
}

__global__ void k9_norm(float* __restrict__ o, const float* __restrict__ mn,
                        const float* __restrict__ mx) {
    int idx = blockIdx.x * 256 + threadIdx.x;
    int ch = idx >> 16;
    float a = mn[ch];
    o[idx] = (o[idx] - a) / (mx[ch] - a);
}

extern "C" void kernel_launch(void* const* d_in, const int* in_sizes, int n_in,
                              void* d_out, int out_size, void* d_ws, size_t ws_size,
                              hipStream_t stream) {
    const float* x      = (const float*)d_in[0];
    const float* weight = (const float*)d_in[1];
    const float* conv_w = (const float*)d_in[2];
    const float* bn_g   = (const float*)d_in[3];
    const float* bn_b   = (const float*)d_in[4];
    const float* bn_m   = (const float*)d_in[5];
    const float* bn_v   = (const float*)d_in[6];
    float* out = (float*)d_out;
    float* ws  = (float*)d_ws;

    double* imga   = (double*)ws;
    float*  pooled = ws + POOLF;
    uchar4* codes  = (uchar4*)(ws + POOLF);            // overlaps pooled; written after K2a
    unsigned char* maskq = (unsigned char*)(ws + MASKQF);
    double* rcs    = (double*)(ws + TRIHF);            // dead before k7a writes triH
    unsigned short* triH = (unsigned short*)(ws + TRIHF);
    unsigned short* triV = (unsigned short*)(ws + TRIVF);
    float*  h2buf  = ws;                               // overlaps imga/pooled (dead by K7c)
    double* partial = (double*)(ws + TAILF);           // 32 doubles
    int*    thrLo   = (int*)(ws + TAILF + 4096);
    int*    thrHi   = thrLo + 32;
    int*    ghist   = thrHi + 32;
    float*  pmn     = (float*)(ghist + 816);           // 10240
    float*  pmx     = pmn + 10240;                     // 10240
    float*  mn      = pmx + 10240;                     // 40
    float*  mx      = mn + 40;                         // 40

    hipMemsetAsync(ghist, 0, 816 * sizeof(int), stream);

    k1_pool3  <<<2048, 256, 0, stream>>>(x, pooled, imga);
    k2a       <<<12288, 256, 0, stream>>>(pooled, rcs);
    k2b       <<<32, 256, 0, stream>>>(rcs, conv_w, partial);
    k3_gl     <<<8192, 256, 0, stream>>>(imga, weight, codes);
    k4_hist   <<<dim3(64, B), 256, 0, stream>>>(codes, ghist);
    k5_thr    <<<B, 128, 0, stream>>>(ghist, partial, bn_g, bn_b, bn_m, bn_v, thrLo, thrHi);
    k6_mask   <<<8192, 256, 0, stream>>>(codes, thrLo, thrHi, maskq);
    k7a       <<<5120, 256, 0, stream>>>(maskq, triH);
    k7b       <<<5120, 256, 0, stream>>>(triH, triV);
    k7c       <<<5120, 256, 0, stream>>>(triV, h2buf);
    k7d       <<<10240, 256, 0, stream>>>(h2buf, out, pmn, pmx);
    k8b       <<<40, 256, 0, stream>>>(pmn, pmx, mn, mx);
    k9_norm   <<<10240, 256, 0, stream>>>(out, mn, mx);
}

// Round 15
// 167.092 us; speedup vs baseline: 2.9555x; 1.1236x over previous
//
#include <hip/hip_runtime.h>
#include <math.h>

// No FMA contraction: decision path rounds every op individually.
#pragma clang fp contract(off)

#define B 8
#define SP2 262144   // 512*512
#define SP3 65536    // 256*256

// ws float-indexed layout (~84 MB):
//  [0, 4194304)            imga f64 [8,512,512]        (K1->K3)
//  [4194304, 10485760)     pooled f32 [8,3,512,512]    (K1->K2a)
//  [4194304, 6291456)      codes uchar4 [8,512,512]    (K3 after K2a; ->K6)
//  [6291456, 8912896)      maskq u8 [8,5,512,512]      (K6 -> K7F)
//  [10485760, 15728640)    rcs f64 [24,512,7]          (K2a->K2b)
//  [20971520, ...)         tail: partial 32 dbl | thrLo 32 | thrHi 32 | ghist 816 |
//                                pmn 1280 f | pmx 1280 f | mn 40 f | mx 40 f
#define POOLF  4194304
#define MASKQF 6291456
#define TRIHF  10485760
#define TAILF  20971520

// ---------------- K1: 3x3 s2 avgpool (f64) + channel mean, 4 outputs/thread, float4 loads ----
__global__ void k1_pool3(const float* __restrict__ x, float* __restrict__ pooled,
                         double* __restrict__ imga) {
    int tid = blockIdx.x * 256 + threadIdx.x;   // [0, 8*512*128): (b, yo, quad)
    int q  = tid & 127;            // quad: outputs xo = 4q .. 4q+3
    int yo = (tid >> 7) & 511;
    int b  = tid >> 16;
    int xb = 8 * q;                // input col base; need cols xb-1 .. xb+7
    double pv[3][4];
    for (int c = 0; c < 3; ++c) {
        const float* p = x + ((size_t)(b * 3 + c)) * 1048576;
        double s0 = 0.0, s1 = 0.0, s2 = 0.0, s3 = 0.0;
        #pragma unroll
        for (int dy = 0; dy < 3; ++dy) {
            int iy = 2 * yo - 1 + dy;
            if ((unsigned)iy >= 1024u) continue;
            const float* row = p + (size_t)iy * 1024 + xb;
            float4 fM = *(const float4*)row;
            float4 fR = *(const float4*)(row + 4);
            float  vm1 = (q > 0) ? row[-1] : 0.f;
            s0 += (double)vm1  + (double)fM.x + (double)fM.y;
            s1 += (double)fM.y + (double)fM.z + (double)fM.w;
            s2 += (double)fM.w + (double)fR.x + (double)fR.y;
            s3 += (double)fR.y + (double)fR.z + (double)fR.w;
        }
        pv[c][0] = s0 / 9.0; pv[c][1] = s1 / 9.0; pv[c][2] = s2 / 9.0; pv[c][3] = s3 / 9.0;
        float4 st = make_float4((float)pv[c][0], (float)pv[c][1], (float)pv[c][2], (float)pv[c][3]);
        *(float4*)(pooled + ((size_t)(b * 3 + c)) * SP2 + yo * 512 + 4 * q) = st;
    }
    double* ia = imga + (size_t)b * SP2 + yo * 512 + 4 * q;
    #pragma unroll
    for (int k = 0; k < 4; ++k)
        ia[k] = ((pv[0][k] + pv[1][k]) + pv[2][k]) / 3.0;
}

// ---------------- K2a: per-(b,c,row) column-sublattice sums for the 7 kx offsets --------------
__global__ void k2a(const float* __restrict__ pooled, double* __restrict__ rcs) {
    int blk = blockIdx.x;            // (b*3+c)*512 + iy,  12288 blocks
    int iy = blk & 511;
    int bc = blk >> 9;
    const float* row = pooled + (size_t)bc * SP2 + iy * 512;
    double v[7] = {0, 0, 0, 0, 0, 0, 0};
    for (int ix = threadIdx.x; ix < 512; ix += 256) {
        double pv = (double)row[ix];
        #pragma unroll
        for (int kx = 0; kx < 7; ++kx) {
            int d = ix - (kx - 3);
            if (d >= 0 && d < 512 && !(d & 1)) v[kx] += pv;
        }
    }
    __shared__ double red[7][256];
    #pragma unroll
    for (int kx = 0; kx < 7; ++kx) red[kx][threadIdx.x] = v[kx];
    __syncthreads();
    for (int s = 128; s > 0; s >>= 1) {
        if (threadIdx.x < s) {
            #pragma unroll
            for (int kx = 0; kx < 7; ++kx)
                red[kx][threadIdx.x] += red[kx][threadIdx.x + s];
        }
        __syncthreads();
    }
    if (threadIdx.x < 7) rcs[(size_t)blk * 7 + threadIdx.x] = red[threadIdx.x][0];
}

// ---------------- K2b: combine -> conv spatial sum per (b, o=1..4), oy-parallel ---------------
__global__ void k2b(const double* __restrict__ rcs, const float* __restrict__ convw,
                    double* __restrict__ partial) {
    int b = blockIdx.x >> 2;
    int o = (blockIdx.x & 3) + 1;
    int t = threadIdx.x;             // t = oy in [0,256)
    double acc = 0.0;
    #pragma unroll 7
    for (int tap = 0; tap < 147; ++tap) {
        int c = tap / 49;
        int k = tap - c * 49;
        int ky = k / 7, kx = k - ky * 7;
        int iy = 2 * t + ky - 3;
        if ((unsigned)iy < 512u) {
            double w = (double)convw[o * 147 + tap];
            acc += w * rcs[((size_t)(b * 3 + c) * 512 + iy) * 7 + kx];
        }
    }
    __shared__ double red[256];
    red[t] = acc;
    __syncthreads();
    for (int s2 = 128; s2 > 0; s2 >>= 1) {
        if (t < s2) red[t] += red[t + s2];
        __syncthreads();
    }
    if (t == 0) partial[blockIdx.x] = red[0];
}

// ---------------- K3: GL conv (f64) -> crisp + fuzzed bin codes ----------------
__global__ void k3_gl(const double* __restrict__ imga, const float* __restrict__ weight,
                      uchar4* __restrict__ codes) {
    __shared__ double xv[101];
    for (int i = threadIdx.x; i < 101; i += 256) {
        double d = (double)i / 100.0;
        xv[i] = (double)(float)(10.0 * d * d * d);
    }
    __syncthreads();
    int idx = blockIdx.x * 256 + threadIdx.x;
    int xo = idx & 511;
    int yo = (idx >> 9) & 511;
    int b  = idx >> 18;
    const double* im = imga + (size_t)b * SP2;
    double GL = (double)weight[0];
    double a1 = GL * 4.0, a2 = -a1 / 8.0, a3 = -a1 / 16.0;
    auto g = [&](int y, int x) -> double {
        if ((unsigned)y >= 512u || (unsigned)x >= 512u) return 0.0;
        return im[y * 512 + x];
    };
    double v = a1 * g(yo, xo)
             + a2 * (g(yo - 1, xo) + g(yo, xo - 1) + g(yo, xo + 1) + g(yo + 1, xo))
             + a3 * (g(yo - 2, xo) + g(yo - 1, xo - 1) + g(yo - 1, xo + 1) + g(yo, xo - 2)
                   + g(yo, xo + 2) + g(yo + 1, xo - 1) + g(yo + 1, xo + 1) + g(yo + 2, xo));
    double t = fabs(v);
    const double EPS = 6e-7;
    // crisp: full binary search (same predicates as before)
    int cM;
    if (t < 1e-6) cM = 255;
    else if (t > xv[100]) cM = 101;
    else {
        int lo = 0, hi = 100;
        while (lo < hi) { int mid = (lo + hi) >> 1; if (t <= xv[mid]) hi = mid; else lo = mid + 1; }
        cM = lo;
    }
    // cA = classify(t-EPS): walk down from cM (bins near cutoff are >> EPS wide)
    double ua = t - EPS;
    int cA;
    if (ua < 1e-6) cA = 255;
    else if (ua > xv[100]) cA = 101;
    else {
        int k = (cM == 101) ? 100 : ((cM == 255) ? 100 : cM);
        while (k > 0 && ua <= xv[k - 1]) --k;
        cA = k;
    }
    // cB = classify(t+EPS): walk up from cM
    double ub = t + EPS;
    int cB;
    if (ub < 1e-6) cB = 255;
    else if (ub > xv[100]) cB = 101;
    else {
        int k = (cM == 255) ? 0 : ((cM == 101) ? 100 : cM);
        while (k < 100 && ub > xv[k]) ++k;
        cB = k;
    }
    codes[idx] = make_uchar4((unsigned char)cM, (unsigned char)cA, (unsigned char)cB, 0);
}

// ---------------- K4: per-batch crisp-code histogram ----------------
__global__ void k4_hist(const uchar4* __restrict__ codes, int* __restrict__ ghist) {
    int b = blockIdx.y;
    __shared__ int h[102];
    for (int i = threadIdx.x; i < 102; i += 256) h[i] = 0;
    __syncthreads();
    const uchar4* cb = codes + (size_t)b * SP2;
    for (int p = blockIdx.x * 256 + threadIdx.x; p < SP2; p += 64 * 256) {
        int c = cb[p].x;
        if (c != 255) atomicAdd(&h[c], 1);
    }
    __syncthreads();
    for (int i = threadIdx.x; i < 102; i += 256)
        if (h[i]) atomicAdd(&ghist[b * 102 + i], h[i]);
}

// ---------------- K5: targets -> argmin with near-tie hedge (LDS, 1 block/batch) ------------
__global__ void k5_thr(const int* __restrict__ ghist, const double* __restrict__ partial,
                       const float* __restrict__ bn_gamma, const float* __restrict__ bn_beta,
                       const float* __restrict__ bn_mean, const float* __restrict__ bn_var,
                       int* __restrict__ thrLo, int* __restrict__ thrHi) {
    int b = blockIdx.x;
    int t = threadIdx.x;            // 128 threads
    __shared__ int    hS[102];
    __shared__ int    cumI[101];
    __shared__ double pct[101];
    __shared__ double ps[4];
    __shared__ int    allS;
    if (t < 102) hS[t] = ghist[b * 102 + t];
    __syncthreads();
    if (t == 0) {
        int all = 0;
        for (int k = 0; k < 102; ++k) all += hS[k];
        allS = all;
        int cum = 0;
        for (int k = 0; k < 101; ++k) { cum += hS[k]; cumI[k] = cum; }
    }
    __syncthreads();
    double alld = (double)allS;
    if (t < 101) pct[t] = (double)cumI[t] / alld;
    if (t < 4) {
        int o = t + 1;
        double s = partial[b * 4 + t];
        double m = s / 65536.0;
        double scale = (double)bn_gamma[o] / sqrt((double)bn_var[o] + 1e-5);
        double val = (m - (double)bn_mean[o]) * scale + (double)bn_beta[o];
        const double base[4] = {0.2, 0.4, 0.6, 0.8};
        ps[t] = base[t] + 0.05 * tanh(val);
    }
    __syncthreads();
    if (t == 0) {
        for (int i = 0; i < 4; ++i)
            for (int j = i + 1; j < 4; ++j)
                if (ps[j] < ps[i]) { double tp = ps[i]; ps[i] = ps[j]; ps[j] = tp; }
    }
    __syncthreads();
    if (t < 4) {
        const double EPS_TIE = 1.2e-7;
        double target = ps[t];
        double best = 1e300; int bi = 0;
        for (int k = 0; k < 101; ++k) {
            double z = fabs(pct[k] - target);
            if (z < best) { best = z; bi = k; }
        }
        int lo = bi, hi = bi;
        for (int k = 0; k < 101; ++k) {
            double z = fabs(pct[k] - target);
            if (z <= best + EPS_TIE) { if (k < lo) lo = k; if (k > hi) hi = k; }
        }
        int cnt = cumI[hi] - cumI[lo];
        if (cnt > 2) { lo = bi; hi = bi; }
        thrLo[b * 4 + t] = lo;
        thrHi[b * 4 + t] = hi;
    }
}

// ---------------- K6: quarter-unit band mask, 4 pixels/thread, uchar4 stores ----------------
__global__ void k6_mask(const uchar4* __restrict__ codes, const int* __restrict__ thrLo,
                        const int* __restrict__ thrHi, unsigned char* __restrict__ mq) {
    int idx4 = blockIdx.x * 256 + threadIdx.x;  // quad index, [0, 524288)
    int b  = idx4 >> 16;                        // SP2/4 = 65536 quads per batch
    int sp0 = (idx4 & 65535) * 4;
    const uchar4* cb = codes + (size_t)b * SP2 + sp0;
    uchar4 cd[4] = {cb[0], cb[1], cb[2], cb[3]};
    const int* tL = thrLo + b * 4;
    const int* tH = thrHi + b * 4;
    int t0L = tL[0], t1L = tL[1], t2L = tL[2], t3L = tL[3];
    int t0H = tH[0], t1H = tH[1], t2H = tH[2], t3H = tH[3];
    unsigned char wv[5][4];
    #pragma unroll
    for (int px = 0; px < 4; ++px) {
        int w0 = 0, w1 = 0, w2 = 0, w3 = 0, w4 = 0;
        int cand[2] = {cd[px].y, cd[px].z};
        #pragma unroll
        for (int ci = 0; ci < 2; ++ci) {
            int c = cand[ci];
            if (c == 255) continue;
            // tL scenario
            if (c <= t0L) ++w0; else if (c <= t1L) ++w1; else if (c <= t2L) ++w2;
            else if (c <= t3L) ++w3; else ++w4;
            // tH scenario
            if (c <= t0H) ++w0; else if (c <= t1H) ++w1; else if (c <= t2H) ++w2;
            else if (c <= t3H) ++w3; else ++w4;
        }
        wv[0][px] = (unsigned char)w0; wv[1][px] = (unsigned char)w1;
        wv[2][px] = (unsigned char)w2; wv[3][px] = (unsigned char)w3;
        wv[4][px] = (unsigned char)w4;
    }
    unsigned char* mb = mq + (size_t)b * 5 * SP2 + sp0;
    #pragma unroll
    for (int pl = 0; pl < 5; ++pl)
        *(uchar4*)(mb + (size_t)pl * SP2) = make_uchar4(wv[pl][0], wv[pl][1], wv[pl][2], wv[pl][3]);
}

// ---------------- K7F: fused pool chain (maskq -> out + per-block min/max), exact int --------
// Per block: 8 final output rows (256 cols) of one channel. All stages in LDS.
__global__ void __launch_bounds__(256) k7f(const unsigned char* __restrict__ mq,
                                           float* __restrict__ out,
                                           float* __restrict__ pmn, float* __restrict__ pmx) {
    __shared__ unsigned short shH[39][512];    // triH rows gr=2y0-12 .. 2y0+26 ; later aliased triV
    __shared__ unsigned short shB[31][512];    // boxV rows j=2y0-8 .. 2y0+22 ; later aliased h2(int)
    __shared__ float smn[256], smx[256];
    unsigned short (*shT)[512] = shH;          // triV rows r=2y0-4 .. 2y0+18 (23 rows)
    int (*shD)[256] = (int (*)[256])shB;       // h2 rows (23 x 256 int)

    int blk = (blockIdx.x & 7) * 160 + (blockIdx.x >> 3);   // bijective XCD swizzle, nwg=1280
    int g  = blk & 31;
    int ch = blk >> 5;
    int y0 = g * 8;
    int tid = threadIdx.x;
    int lane = tid & 63;
    int rsel = tid >> 6;

    // ---- Stage A: horizontal 17-tap triangle for 39 rows -> shH ----
    for (int it = 0; it < 10; ++it) {
        int rl = 4 * it + rsel;
        if (rl >= 39) break;
        int gr = 2 * y0 - 12 + rl;
        int x0 = lane * 8;
        uint4 pk = make_uint4(0u, 0u, 0u, 0u);
        if ((unsigned)gr < 512u) {
            const uint2* r8 = (const uint2*)(mq + (size_t)ch * SP2 + (size_t)gr * 512);
            uint2 cL = (lane > 0)  ? r8[lane - 1] : make_uint2(0u, 0u);
            uint2 cM = r8[lane];
            uint2 cR = (lane < 63) ? r8[lane + 1] : make_uint2(0u, 0u);
            int v[24];
            auto unpack = [](uint2 c, int* dst) {
                dst[0] = c.x & 255; dst[1] = (c.x >> 8) & 255; dst[2] = (c.x >> 16) & 255; dst[3] = (c.x >> 24) & 255;
                dst[4] = c.y & 255; dst[5] = (c.y >> 8) & 255; dst[6] = (c.y >> 16) & 255; dst[7] = (c.y >> 24) & 255;
            };
            unpack(cL, v); unpack(cM, v + 8); unpack(cR, v + 16);
            int bx[16];
            int s = 0;
            #pragma unroll
            for (int i = 0; i < 9; ++i) s += v[i];
            bx[0] = s;
            #pragma unroll
            for (int k = 1; k < 16; ++k) { s += v[k + 8] - v[k - 1]; bx[k] = s; }
            if (lane == 0)  { bx[0] = 0; bx[1] = 0; bx[2] = 0; bx[3] = 0; }
            if (lane == 63) { bx[12] = 0; bx[13] = 0; bx[14] = 0; bx[15] = 0; }
            int t = 0;
            #pragma unroll
            for (int i = 0; i < 9; ++i) t += bx[i];
            unsigned short o[8];
            o[0] = (unsigned short)t;
            #pragma unroll
            for (int i = 1; i < 8; ++i) { t += bx[i + 8] - bx[i - 1]; o[i] = (unsigned short)t; }
            pk.x = (unsigned)o[0] | ((unsigned)o[1] << 16);
            pk.y = (unsigned)o[2] | ((unsigned)o[3] << 16);
            pk.z = (unsigned)o[4] | ((unsigned)o[5] << 16);
            pk.w = (unsigned)o[6] | ((unsigned)o[7] << 16);
        }
        *(uint4*)&shH[rl][x0] = pk;
    }
    __syncthreads();

    // ---- Stage B: vertical box9 for 31 center rows -> shB (zero OOB centers) ----
    #pragma unroll
    for (int half = 0; half < 2; ++half) {
        int x = tid + half * 256;
        int s = 0;
        #pragma unroll
        for (int i = 0; i < 9; ++i) s += (int)shH[i][x];
        int j0 = 2 * y0 - 8;
        shB[0][x] = (unsigned short)(((unsigned)j0 < 512u) ? s : 0);
        #pragma unroll
        for (int jl = 1; jl < 31; ++jl) {
            s += (int)shH[jl + 8][x] - (int)shH[jl - 1][x];
            int j = j0 + jl;
            shB[jl][x] = (unsigned short)(((unsigned)j < 512u) ? s : 0);
        }
    }
    __syncthreads();

    // ---- Stage C: vertical box9 of shB -> triV (23 rows) into shT (aliases shH) ----
    #pragma unroll
    for (int half = 0; half < 2; ++half) {
        int x = tid + half * 256;
        int s = 0;
        #pragma unroll
        for (int i = 0; i < 9; ++i) s += (int)shB[i][x];
        unsigned short tv[23];
        tv[0] = (unsigned short)s;
        #pragma unroll
        for (int rl = 1; rl < 23; ++rl) {
            s += (int)shB[rl + 8][x] - (int)shB[rl - 1][x];
            tv[rl] = (unsigned short)s;
        }
        __syncthreads();          // all reads of shB/shH done before overwriting shT(=shH)
        #pragma unroll
        for (int rl = 0; rl < 23; ++rl) shT[rl][x] = tv[rl];
        if (half == 0) __syncthreads();   // keep both halves in lockstep w.r.t. shB reads
    }
    __syncthreads();

    // ---- Stage D: horizontal box9 stride-2 -> shD (23 x 256 int, aliases shB) ----
    for (int it = 0; it < 6; ++it) {
        int rl = 4 * it + rsel;
        if (rl >= 23) break;
        int gr = 2 * y0 - 4 + rl;
        int ox0 = lane * 4;
        int o0 = 0, o1 = 0, o2 = 0, o3 = 0;
        if ((unsigned)gr < 512u) {
            int v[15];
            #pragma unroll
            for (int i = 0; i < 15; ++i) {
                int ix = 2 * ox0 - 4 + i;
                v[i] = ((unsigned)ix < 512u) ? (int)shT[rl][ix] : 0;
            }
            int s = 0;
            #pragma unroll
            for (int i = 0; i < 9; ++i) s += v[i];
            o0 = s;
            s += v[9] + v[10] - v[0] - v[1];   o1 = s;
            s += v[11] + v[12] - v[2] - v[3];  o2 = s;
            s += v[13] + v[14] - v[4] - v[5];  o3 = s;
        }
        shD[rl][ox0] = o0; shD[rl][ox0 + 1] = o1; shD[rl][ox0 + 2] = o2; shD[rl][ox0 + 3] = o3;
    }
    __syncthreads();

    // ---- Stage E: vertical box9 stride-2 -> out, track block min/max ----
    int x = tid;
    float lmn = 3.4e38f, lmx = -3.4e38f;
    float* op = out + (size_t)ch * SP3 + (size_t)y0 * 256 + x;
    #pragma unroll
    for (int dy = 0; dy < 8; ++dy) {
        int s = 0;
        #pragma unroll
        for (int d = 0; d < 9; ++d) s += shD[2 * dy + d][x];
        float val = (float)s / 2125764.0f;   // 4 * 81^3
        op[(size_t)dy * 256] = val;
        lmn = fminf(lmn, val); lmx = fmaxf(lmx, val);
    }
    smn[tid] = lmn; smx[tid] = lmx;
    __syncthreads();
    for (int st = 128; st > 0; st >>= 1) {
        if (tid < st) {
            smn[tid] = fminf(smn[tid], smn[tid + st]);
            smx[tid] = fmaxf(smx[tid], smx[tid + st]);
        }
        __syncthreads();
    }
    if (tid == 0) { pmn[blk] = smn[0]; pmx[blk] = smx[0]; }
}

// ---------------- K8b: reduce 32 partials per channel (atomic-free) ----------------
__global__ void k8b(const float* __restrict__ pmn, const float* __restrict__ pmx,
                    float* __restrict__ mn, float* __restrict__ mx) {
    int ch = blockIdx.x;
    int t = threadIdx.x;   // 64 threads
    __shared__ float smn[64], smx[64];
    smn[t] = (t < 32) ? pmn[ch * 32 + t] : 3.4e38f;
    smx[t] = (t < 32) ? pmx[ch * 32 + t] : -3.4e38f;
    __syncthreads();
    for (int st = 32; st > 0; st >>= 1) {
        if (t < st) {
            smn[t] = fminf(smn[t], smn[t + st]);
            smx[t] = fmaxf(smx[t], smx[t + st]);
        }
        __syncthreads();
    }
    if (t == 0) { mn[ch] = smn[0]; mx[ch] = smx[0]; }
}

__global__ void k9_norm(float* __restrict__ o, const float* __restrict__ mn,
                        const float* __restrict__ mx) {
    int idx = blockIdx.x * 256 + threadIdx.x;
    int ch = idx >> 16;
    float a = mn[ch];
    o[idx] = (o[idx] - a) / (mx[ch] - a);
}

extern "C" void kernel_launch(void* const* d_in, const int* in_sizes, int n_in,
                              void* d_out, int out_size, void* d_ws, size_t ws_size,
                              hipStream_t stream) {
    const float* x      = (const float*)d_in[0];
    const float* weight = (const float*)d_in[1];
    const float* conv_w = (const float*)d_in[2];
    const float* bn_g   = (const float*)d_in[3];
    const float* bn_b   = (const float*)d_in[4];
    const float* bn_m   = (const float*)d_in[5];
    const float* bn_v   = (const float*)d_in[6];
    float* out = (float*)d_out;
    float* ws  = (float*)d_ws;

    double* imga   = (double*)ws;
    float*  pooled = ws + POOLF;
    uchar4* codes  = (uchar4*)(ws + POOLF);            // overlaps pooled; written after K2a
    unsigned char* maskq = (unsigned char*)(ws + MASKQF);
    double* rcs    = (double*)(ws + TRIHF);
    double* partial = (double*)(ws + TAILF);           // 32 doubles
    int*    thrLo   = (int*)(ws + TAILF + 4096);
    int*    thrHi   = thrLo + 32;
    int*    ghist   = thrHi + 32;
    float*  pmn     = (float*)(ghist + 816);           // 1280
    float*  pmx     = pmn + 1280;                      // 1280
    float*  mn      = pmx + 1280;                      // 40
    float*  mx      = mn + 40;                         // 40

    hipMemsetAsync(ghist, 0, 816 * sizeof(int), stream);

    k1_pool3  <<<2048, 256, 0, stream>>>(x, pooled, imga);
    k2a       <<<12288, 256, 0, stream>>>(pooled, rcs);
    k2b       <<<32, 256, 0, stream>>>(rcs, conv_w, partial);
    k3_gl     <<<8192, 256, 0, stream>>>(imga, weight, codes);
    k4_hist   <<<dim3(64, B), 256, 0, stream>>>(codes, ghist);
    k5_thr    <<<B, 128, 0, stream>>>(ghist, partial, bn_g, bn_b, bn_m, bn_v, thrLo, thrHi);
    k6_mask   <<<2048, 256, 0, stream>>>(codes, thrLo, thrHi, maskq);
    k7f       <<<1280, 256, 0, stream>>>(maskq, out, pmn, pmx);
    k8b       <<<40, 64, 0, stream>>>(pmn, pmx, mn, mx);
    k9_norm   <<<10240, 256, 0, stream>>>(out, mn, mx);
}

// Round 16
// 140.367 us; speedup vs baseline: 3.5182x; 1.1904x over previous
//
#include <hip/hip_runtime.h>
#include <math.h>

// No FMA contraction: decision path rounds every op individually.
#pragma clang fp contract(off)

#define B 8
#define SP2 262144   // 512*512
#define SP3 65536    // 256*256

// ws float-indexed layout:
//  [0, 4194304)            imga f64 [8,512,512]        (K1->K3)
//  [4194304, 6291456)      codes uchar4 [8,512,512]    (K3 ->K6)
//  [6291456, 8912896)      maskq u8 [8,5,512,512]      (K6 -> K7F)
//  [10485760, 15728640)    rcs f64 [24,512,7]          (K1->K2b)
//  [20971520, ...)         tail: partial 32 dbl | thrLo 32 | thrHi 32 | ghist 816 |
//                                pmn 1280 f | pmx 1280 f
#define POOLF  4194304
#define MASKQF 6291456
#define TRIHF  10485760
#define TAILF  20971520

// ---------------- K1: 3x3 s2 avgpool (f64) + channel mean + fused per-row sublattice sums ----
// Block = 2 full rows (all 3 channels). rcs written directly; `pooled` eliminated.
__global__ void k1_pool3(const float* __restrict__ x, double* __restrict__ imga,
                         double* __restrict__ rcs) {
    __shared__ double redE[2][3][128], redO[2][3][128];
    __shared__ double edge[2][3][5];   // col0, col1, col509, col510, col511
    int tid = threadIdx.x;
    int q = tid & 127;                 // quad: outputs xo = 4q .. 4q+3
    int r = tid >> 7;                  // row-in-block
    int rowIdx = blockIdx.x * 2 + r;   // [0, 4096)
    int yo = rowIdx & 511;
    int b  = rowIdx >> 9;
    int xb = 8 * q;
    double pv[3][4];
    for (int c = 0; c < 3; ++c) {
        const float* p = x + ((size_t)(b * 3 + c)) * 1048576;
        double s0 = 0.0, s1 = 0.0, s2 = 0.0, s3 = 0.0;
        #pragma unroll
        for (int dy = 0; dy < 3; ++dy) {
            int iy = 2 * yo - 1 + dy;
            if ((unsigned)iy >= 1024u) continue;
            const float* row = p + (size_t)iy * 1024 + xb;
            float4 fM = *(const float4*)row;
            float4 fR = *(const float4*)(row + 4);
            float  vm1 = (q > 0) ? row[-1] : 0.f;
            s0 += (double)vm1  + (double)fM.x + (double)fM.y;
            s1 += (double)fM.y + (double)fM.z + (double)fM.w;
            s2 += (double)fM.w + (double)fR.x + (double)fR.y;
            s3 += (double)fR.y + (double)fR.z + (double)fR.w;
        }
        pv[c][0] = s0 * (1.0 / 9.0); pv[c][1] = s1 * (1.0 / 9.0);
        pv[c][2] = s2 * (1.0 / 9.0); pv[c][3] = s3 * (1.0 / 9.0);
        redE[r][c][q] = pv[c][0] + pv[c][2];
        redO[r][c][q] = pv[c][1] + pv[c][3];
        if (q == 0)   { edge[r][c][0] = pv[c][0]; edge[r][c][1] = pv[c][1]; }
        if (q == 127) { edge[r][c][2] = pv[c][1]; edge[r][c][3] = pv[c][2]; edge[r][c][4] = pv[c][3]; }
    }
    double* ia = imga + (size_t)b * SP2 + yo * 512 + 4 * q;
    #pragma unroll
    for (int k = 0; k < 4; ++k)
        ia[k] = ((pv[0][k] + pv[1][k]) + pv[2][k]) * (1.0 / 3.0);
    __syncthreads();
    for (int s = 64; s > 0; s >>= 1) {
        if (q < s) {
            #pragma unroll
            for (int c = 0; c < 3; ++c) {
                redE[r][c][q] += redE[r][c][q + s];
                redO[r][c][q] += redO[r][c][q + s];
            }
        }
        __syncthreads();
    }
    if (q < 21) {
        int c = q / 7, kx = q - c * 7;
        double E = redE[r][c][0], O = redO[r][c][0];
        double val;
        switch (kx) {
            case 0: val = O - edge[r][c][2] - edge[r][c][4]; break;  // odd <=507
            case 1: val = E - edge[r][c][3]; break;                  // even <=508
            case 2: val = O - edge[r][c][4]; break;                  // odd <=509
            case 3: val = E; break;                                  // all even
            case 4: val = O; break;                                  // all odd
            case 5: val = E - edge[r][c][0]; break;                  // even >=2
            default: val = O - edge[r][c][1]; break;                 // odd >=3
        }
        rcs[((size_t)(b * 3 + c) * 512 + yo) * 7 + kx] = val;
    }
}

// ---------------- K2b: combine -> conv spatial sum per (b, o=1..4), oy-parallel ---------------
__global__ void k2b(const double* __restrict__ rcs, const float* __restrict__ convw,
                    double* __restrict__ partial) {
    int b = blockIdx.x >> 2;
    int o = (blockIdx.x & 3) + 1;
    int t = threadIdx.x;             // t = oy in [0,256)
    double acc = 0.0;
    #pragma unroll 7
    for (int tap = 0; tap < 147; ++tap) {
        int c = tap / 49;
        int k = tap - c * 49;
        int ky = k / 7, kx = k - ky * 7;
        int iy = 2 * t + ky - 3;
        if ((unsigned)iy < 512u) {
            double w = (double)convw[o * 147 + tap];
            acc += w * rcs[((size_t)(b * 3 + c) * 512 + iy) * 7 + kx];
        }
    }
    __shared__ double red[256];
    red[t] = acc;
    __syncthreads();
    for (int s2 = 128; s2 > 0; s2 >>= 1) {
        if (t < s2) red[t] += red[t + s2];
        __syncthreads();
    }
    if (t == 0) partial[blockIdx.x] = red[0];
}

// ---------------- K3: GL conv (f64) -> crisp + fuzzed bin codes ----------------
__global__ void k3_gl(const double* __restrict__ imga, const float* __restrict__ weight,
                      uchar4* __restrict__ codes) {
    __shared__ double xv[101];
    for (int i = threadIdx.x; i < 101; i += 256) {
        double d = (double)i / 100.0;
        xv[i] = (double)(float)(10.0 * d * d * d);
    }
    __syncthreads();
    int idx = blockIdx.x * 256 + threadIdx.x;
    int xo = idx & 511;
    int yo = (idx >> 9) & 511;
    int b  = idx >> 18;
    const double* im = imga + (size_t)b * SP2;
    double GL = (double)weight[0];
    double a1 = GL * 4.0, a2 = -a1 / 8.0, a3 = -a1 / 16.0;
    auto g = [&](int y, int x) -> double {
        if ((unsigned)y >= 512u || (unsigned)x >= 512u) return 0.0;
        return im[y * 512 + x];
    };
    double v = a1 * g(yo, xo)
             + a2 * (g(yo - 1, xo) + g(yo, xo - 1) + g(yo, xo + 1) + g(yo + 1, xo))
             + a3 * (g(yo - 2, xo) + g(yo - 1, xo - 1) + g(yo - 1, xo + 1) + g(yo, xo - 2)
                   + g(yo, xo + 2) + g(yo + 1, xo - 1) + g(yo + 1, xo + 1) + g(yo + 2, xo));
    double t = fabs(v);
    const double EPS = 6e-7;
    int cM;
    if (t < 1e-6) cM = 255;
    else if (t > xv[100]) cM = 101;
    else {
        int lo = 0, hi = 100;
        while (lo < hi) { int mid = (lo + hi) >> 1; if (t <= xv[mid]) hi = mid; else lo = mid + 1; }
        cM = lo;
    }
    double ua = t - EPS;
    int cA;
    if (ua < 1e-6) cA = 255;
    else if (ua > xv[100]) cA = 101;
    else {
        int k = (cM == 101) ? 100 : ((cM == 255) ? 100 : cM);
        while (k > 0 && ua <= xv[k - 1]) --k;
        cA = k;
    }
    double ub = t + EPS;
    int cB;
    if (ub < 1e-6) cB = 255;
    else if (ub > xv[100]) cB = 101;
    else {
        int k = (cM == 255) ? 0 : ((cM == 101) ? 100 : cM);
        while (k < 100 && ub > xv[k]) ++k;
        cB = k;
    }
    codes[idx] = make_uchar4((unsigned char)cM, (unsigned char)cA, (unsigned char)cB, 0);
}

// ---------------- K4: per-batch crisp-code histogram ----------------
__global__ void k4_hist(const uchar4* __restrict__ codes, int* __restrict__ ghist) {
    int b = blockIdx.y;
    __shared__ int h[102];
    for (int i = threadIdx.x; i < 102; i += 256) h[i] = 0;
    __syncthreads();
    const uchar4* cb = codes + (size_t)b * SP2;
    for (int p = blockIdx.x * 256 + threadIdx.x; p < SP2; p += 64 * 256) {
        int c = cb[p].x;
        if (c != 255) atomicAdd(&h[c], 1);
    }
    __syncthreads();
    for (int i = threadIdx.x; i < 102; i += 256)
        if (h[i]) atomicAdd(&ghist[b * 102 + i], h[i]);
}

// ---------------- K5: targets -> argmin with near-tie hedge (LDS, 1 block/batch) ------------
__global__ void k5_thr(const int* __restrict__ ghist, const double* __restrict__ partial,
                       const float* __restrict__ bn_gamma, const float* __restrict__ bn_beta,
                       const float* __restrict__ bn_mean, const float* __restrict__ bn_var,
                       int* __restrict__ thrLo, int* __restrict__ thrHi) {
    int b = blockIdx.x;
    int t = threadIdx.x;            // 128 threads
    __shared__ int    hS[102];
    __shared__ int    cumI[101];
    __shared__ double pct[101];
    __shared__ double ps[4];
    __shared__ int    allS;
    if (t < 102) hS[t] = ghist[b * 102 + t];
    __syncthreads();
    if (t == 0) {
        int all = 0;
        for (int k = 0; k < 102; ++k) all += hS[k];
        allS = all;
        int cum = 0;
        for (int k = 0; k < 101; ++k) { cum += hS[k]; cumI[k] = cum; }
    }
    __syncthreads();
    double alld = (double)allS;
    if (t < 101) pct[t] = (double)cumI[t] / alld;
    if (t < 4) {
        int o = t + 1;
        double s = partial[b * 4 + t];
        double m = s / 65536.0;
        double scale = (double)bn_gamma[o] / sqrt((double)bn_var[o] + 1e-5);
        double val = (m - (double)bn_mean[o]) * scale + (double)bn_beta[o];
        const double base[4] = {0.2, 0.4, 0.6, 0.8};
        ps[t] = base[t] + 0.05 * tanh(val);
    }
    __syncthreads();
    if (t == 0) {
        for (int i = 0; i < 4; ++i)
            for (int j = i + 1; j < 4; ++j)
                if (ps[j] < ps[i]) { double tp = ps[i]; ps[i] = ps[j]; ps[j] = tp; }
    }
    __syncthreads();
    if (t < 4) {
        const double EPS_TIE = 1.2e-7;
        double target = ps[t];
        double best = 1e300; int bi = 0;
        for (int k = 0; k < 101; ++k) {
            double z = fabs(pct[k] - target);
            if (z < best) { best = z; bi = k; }
        }
        int lo = bi, hi = bi;
        for (int k = 0; k < 101; ++k) {
            double z = fabs(pct[k] - target);
            if (z <= best + EPS_TIE) { if (k < lo) lo = k; if (k > hi) hi = k; }
        }
        int cnt = cumI[hi] - cumI[lo];
        if (cnt > 2) { lo = bi; hi = bi; }
        thrLo[b * 4 + t] = lo;
        thrHi[b * 4 + t] = hi;
    }
}

// ---------------- K6: quarter-unit band mask, 4 pixels/thread, uchar4 stores ----------------
__global__ void k6_mask(const uchar4* __restrict__ codes, const int* __restrict__ thrLo,
                        const int* __restrict__ thrHi, unsigned char* __restrict__ mq) {
    int idx4 = blockIdx.x * 256 + threadIdx.x;  // quad index, [0, 524288)
    int b  = idx4 >> 16;
    int sp0 = (idx4 & 65535) * 4;
    const uchar4* cb = codes + (size_t)b * SP2 + sp0;
    uchar4 cd[4] = {cb[0], cb[1], cb[2], cb[3]};
    const int* tL = thrLo + b * 4;
    const int* tH = thrHi + b * 4;
    int t0L = tL[0], t1L = tL[1], t2L = tL[2], t3L = tL[3];
    int t0H = tH[0], t1H = tH[1], t2H = tH[2], t3H = tH[3];
    unsigned char wv[5][4];
    #pragma unroll
    for (int px = 0; px < 4; ++px) {
        int w0 = 0, w1 = 0, w2 = 0, w3 = 0, w4 = 0;
        int cand[2] = {cd[px].y, cd[px].z};
        #pragma unroll
        for (int ci = 0; ci < 2; ++ci) {
            int c = cand[ci];
            if (c == 255) continue;
            if (c <= t0L) ++w0; else if (c <= t1L) ++w1; else if (c <= t2L) ++w2;
            else if (c <= t3L) ++w3; else ++w4;
            if (c <= t0H) ++w0; else if (c <= t1H) ++w1; else if (c <= t2H) ++w2;
            else if (c <= t3H) ++w3; else ++w4;
        }
        wv[0][px] = (unsigned char)w0; wv[1][px] = (unsigned char)w1;
        wv[2][px] = (unsigned char)w2; wv[3][px] = (unsigned char)w3;
        wv[4][px] = (unsigned char)w4;
    }
    unsigned char* mb = mq + (size_t)b * 5 * SP2 + sp0;
    #pragma unroll
    for (int pl = 0; pl < 5; ++pl)
        *(uchar4*)(mb + (size_t)pl * SP2) = make_uchar4(wv[pl][0], wv[pl][1], wv[pl][2], wv[pl][3]);
}

// ---------------- K7F: fused pool chain (maskq -> out + per-block min/max), exact int --------
__global__ void __launch_bounds__(256) k7f(const unsigned char* __restrict__ mq,
                                           float* __restrict__ out,
                                           float* __restrict__ pmn, float* __restrict__ pmx) {
    __shared__ unsigned short shH[39][512];
    __shared__ unsigned short shB[31][512];
    __shared__ float smn[256], smx[256];
    unsigned short (*shT)[512] = shH;
    int (*shD)[256] = (int (*)[256])shB;

    int blk = (blockIdx.x & 7) * 160 + (blockIdx.x >> 3);   // bijective XCD swizzle, nwg=1280
    int g  = blk & 31;
    int ch = blk >> 5;
    int y0 = g * 8;
    int tid = threadIdx.x;
    int lane = tid & 63;
    int rsel = tid >> 6;

    for (int it = 0; it < 10; ++it) {
        int rl = 4 * it + rsel;
        if (rl >= 39) break;
        int gr = 2 * y0 - 12 + rl;
        int x0 = lane * 8;
        uint4 pk = make_uint4(0u, 0u, 0u, 0u);
        if ((unsigned)gr < 512u) {
            const uint2* r8 = (const uint2*)(mq + (size_t)ch * SP2 + (size_t)gr * 512);
            uint2 cL = (lane > 0)  ? r8[lane - 1] : make_uint2(0u, 0u);
            uint2 cM = r8[lane];
            uint2 cR = (lane < 63) ? r8[lane + 1] : make_uint2(0u, 0u);
            int v[24];
            auto unpack = [](uint2 c, int* dst) {
                dst[0] = c.x & 255; dst[1] = (c.x >> 8) & 255; dst[2] = (c.x >> 16) & 255; dst[3] = (c.x >> 24) & 255;
                dst[4] = c.y & 255; dst[5] = (c.y >> 8) & 255; dst[6] = (c.y >> 16) & 255; dst[7] = (c.y >> 24) & 255;
            };
            unpack(cL, v); unpack(cM, v + 8); unpack(cR, v + 16);
            int bx[16];
            int s = 0;
            #pragma unroll
            for (int i = 0; i < 9; ++i) s += v[i];
            bx[0] = s;
            #pragma unroll
            for (int k = 1; k < 16; ++k) { s += v[k + 8] - v[k - 1]; bx[k] = s; }
            if (lane == 0)  { bx[0] = 0; bx[1] = 0; bx[2] = 0; bx[3] = 0; }
            if (lane == 63) { bx[12] = 0; bx[13] = 0; bx[14] = 0; bx[15] = 0; }
            int t = 0;
            #pragma unroll
            for (int i = 0; i < 9; ++i) t += bx[i];
            unsigned short o[8];
            o[0] = (unsigned short)t;
            #pragma unroll
            for (int i = 1; i < 8; ++i) { t += bx[i + 8] - bx[i - 1]; o[i] = (unsigned short)t; }
            pk.x = (unsigned)o[0] | ((unsigned)o[1] << 16);
            pk.y = (unsigned)o[2] | ((unsigned)o[3] << 16);
            pk.z = (unsigned)o[4] | ((unsigned)o[5] << 16);
            pk.w = (unsigned)o[6] | ((unsigned)o[7] << 16);
        }
        *(uint4*)&shH[rl][x0] = pk;
    }
    __syncthreads();

    #pragma unroll
    for (int half = 0; half < 2; ++half) {
        int x = tid + half * 256;
        int s = 0;
        #pragma unroll
        for (int i = 0; i < 9; ++i) s += (int)shH[i][x];
        int j0 = 2 * y0 - 8;
        shB[0][x] = (unsigned short)(((unsigned)j0 < 512u) ? s : 0);
        #pragma unroll
        for (int jl = 1; jl < 31; ++jl) {
            s += (int)shH[jl + 8][x] - (int)shH[jl - 1][x];
            int j = j0 + jl;
            shB[jl][x] = (unsigned short)(((unsigned)j < 512u) ? s : 0);
        }
    }
    __syncthreads();

    #pragma unroll
    for (int half = 0; half < 2; ++half) {
        int x = tid + half * 256;
        int s = 0;
        #pragma unroll
        for (int i = 0; i < 9; ++i) s += (int)shB[i][x];
        unsigned short tv[23];
        tv[0] = (unsigned short)s;
        #pragma unroll
        for (int rl = 1; rl < 23; ++rl) {
            s += (int)shB[rl + 8][x] - (int)shB[rl - 1][x];
            tv[rl] = (unsigned short)s;
        }
        __syncthreads();
        #pragma unroll
        for (int rl = 0; rl < 23; ++rl) shT[rl][x] = tv[rl];
        if (half == 0) __syncthreads();
    }
    __syncthreads();

    for (int it = 0; it < 6; ++it) {
        int rl = 4 * it + rsel;
        if (rl >= 23) break;
        int gr = 2 * y0 - 4 + rl;
        int ox0 = lane * 4;
        int o0 = 0, o1 = 0, o2 = 0, o3 = 0;
        if ((unsigned)gr < 512u) {
            int v[15];
            #pragma unroll
            for (int i = 0; i < 15; ++i) {
                int ix = 2 * ox0 - 4 + i;
                v[i] = ((unsigned)ix < 512u) ? (int)shT[rl][ix] : 0;
            }
            int s = 0;
            #pragma unroll
            for (int i = 0; i < 9; ++i) s += v[i];
            o0 = s;
            s += v[9] + v[10] - v[0] - v[1];   o1 = s;
            s += v[11] + v[12] - v[2] - v[3];  o2 = s;
            s += v[13] + v[14] - v[4] - v[5];  o3 = s;
        }
        shD[rl][ox0] = o0; shD[rl][ox0 + 1] = o1; shD[rl][ox0 + 2] = o2; shD[rl][ox0 + 3] = o3;
    }
    __syncthreads();

    int x = tid;
    float lmn = 3.4e38f, lmx = -3.4e38f;
    float* op = out + (size_t)ch * SP3 + (size_t)y0 * 256 + x;
    #pragma unroll
    for (int dy = 0; dy < 8; ++dy) {
        int s = 0;
        #pragma unroll
        for (int d = 0; d < 9; ++d) s += shD[2 * dy + d][x];
        float val = (float)s / 2125764.0f;
        op[(size_t)dy * 256] = val;
        lmn = fminf(lmn, val); lmx = fmaxf(lmx, val);
    }
    smn[tid] = lmn; smx[tid] = lmx;
    __syncthreads();
    for (int st = 128; st > 0; st >>= 1) {
        if (tid < st) {
            smn[tid] = fminf(smn[tid], smn[tid + st]);
            smx[tid] = fmaxf(smx[tid], smx[tid + st]);
        }
        __syncthreads();
    }
    if (tid == 0) { pmn[blk] = smn[0]; pmx[blk] = smx[0]; }
}

// ---------------- K9: normalize, with in-block reduce of the 32 per-channel partials --------
__global__ void k9_norm(float* __restrict__ o, const float* __restrict__ pmn,
                        const float* __restrict__ pmx) {
    __shared__ float sm[2];
    int idx = blockIdx.x * 256 + threadIdx.x;
    int ch = idx >> 16;                       // 256 blocks per channel
    int lane = threadIdx.x & 63;
    if (threadIdx.x < 64) {
        float v = (lane < 32) ? pmn[ch * 32 + lane] : pmx[ch * 32 + (lane - 32)];
        #pragma unroll
        for (int off = 16; off > 0; off >>= 1) {
            float u = __shfl_xor(v, off, 64);
            v = (lane < 32) ? fminf(v, u) : fmaxf(v, u);
        }
        if (lane == 0)  sm[0] = v;
        if (lane == 32) sm[1] = v;
    }
    __syncthreads();
    float a = sm[0];
    float bmax = sm[1];
    o[idx] = (o[idx] - a) / (bmax - a);
}

extern "C" void kernel_launch(void* const* d_in, const int* in_sizes, int n_in,
                              void* d_out, int out_size, void* d_ws, size_t ws_size,
                              hipStream_t stream) {
    const float* x      = (const float*)d_in[0];
    const float* weight = (const float*)d_in[1];
    const float* conv_w = (const float*)d_in[2];
    const float* bn_g   = (const float*)d_in[3];
    const float* bn_b   = (const float*)d_in[4];
    const float* bn_m   = (const float*)d_in[5];
    const float* bn_v   = (const float*)d_in[6];
    float* out = (float*)d_out;
    float* ws  = (float*)d_ws;

    double* imga   = (double*)ws;
    uchar4* codes  = (uchar4*)(ws + POOLF);
    unsigned char* maskq = (unsigned char*)(ws + MASKQF);
    double* rcs    = (double*)(ws + TRIHF);
    double* partial = (double*)(ws + TAILF);           // 32 doubles
    int*    thrLo   = (int*)(ws + TAILF + 4096);
    int*    thrHi   = thrLo + 32;
    int*    ghist   = thrHi + 32;
    float*  pmn     = (float*)(ghist + 816);           // 1280
    float*  pmx     = pmn + 1280;                      // 1280

    hipMemsetAsync(ghist, 0, 816 * sizeof(int), stream);

    k1_pool3  <<<2048, 256, 0, stream>>>(x, imga, rcs);
    k2b       <<<32, 256, 0, stream>>>(rcs, conv_w, partial);
    k3_gl     <<<8192, 256, 0, stream>>>(imga, weight, codes);
    k4_hist   <<<dim3(64, B), 256, 0, stream>>>(codes, ghist);
    k5_thr    <<<B, 128, 0, stream>>>(ghist, partial, bn_g, bn_b, bn_m, bn_v, thrLo, thrHi);
    k6_mask   <<<2048, 256, 0, stream>>>(codes, thrLo, thrHi, maskq);
    k7f       <<<1280, 256, 0, stream>>>(maskq, out, pmn, pmx);
    k9_norm   <<<10240, 256, 0, stream>>>(out, pmn, pmx);
}